// Round 15
// baseline (48.636 us; speedup 1.0000x reference)
//
#include <hip/hip_runtime.h>
#include <hip/hip_bf16.h>

#define SPATIAL_SCALE 0.0625f
#define PH 7
#define PW 7
#define C_TOTAL 1024
#define NXCD 8
#define NPOS 49
#define CG 128
#define HH 50
#define WW 50
#define TB_BYTES (2ULL * NXCD * HH * WW * CG * 2ULL)   // 10,240,000 B (bf16)

typedef short bf16x8 __attribute__((ext_vector_type(8)));
typedef float f32x16 __attribute__((ext_vector_type(16)));
typedef float f4a __attribute__((ext_vector_type(4), aligned(16)));
typedef float f4u __attribute__((ext_vector_type(4), aligned(4)));
typedef float f4v __attribute__((ext_vector_type(4), aligned(8)));
typedef unsigned int u4v __attribute__((ext_vector_type(4), aligned(16)));
typedef unsigned int u2v __attribute__((ext_vector_type(2), aligned(8)));

// ---- Kernel 1: NCHW fp32 -> [b][g][y][x][c128] bf16 channels-last ----------
__global__ __launch_bounds__(256) void transpose_bf16_kernel(
    const float* __restrict__ in, __hip_bfloat16* __restrict__ Tb)
{
    __shared__ float lds[CG][WW + 1];
    int bid = blockIdx.x;            // (b*50 + y)*8 + g
    int g = bid & 7;
    int r = bid >> 3;
    int y = r % HH;
    int b = r / HH;
    int tid = threadIdx.x;

    const float* src = in + (size_t)(b * C_TOTAL + g * CG) * (HH * WW) + y * WW;
    #pragma unroll
    for (int it = 0; it < 25; ++it) {        // 6400 = 128c x 50x
        int idx = it * 256 + tid;
        int c = idx / WW;
        int x = idx - c * WW;
        lds[c][x] = src[c * (HH * WW) + x];
    }
    __syncthreads();
    __hip_bfloat16* dst = Tb + (size_t)((b * NXCD + g) * (HH * WW) + y * WW) * CG;
    #pragma unroll
    for (int it = 0; it < 25; ++it) {
        int idx = it * 256 + tid;
        int x = idx >> 7;                    // 0..49
        int c = idx & 127;
        dst[x * CG + c] = __float2bfloat16(lds[c][x]);
    }
}

// ---- Kernel 2: MFMA ROI align v3 ------------------------------------------
// Block = (roi n, slab g): 128 ch, 4 waves. blockIdx&7=g -> XCD pin.
// Tiling: wave w = ONE N-tile (ch = w*32+lane31), TWO M-tiles per wave
// (bins lane31 / lane31+32) -> B read once per kl feeds 2 MFMAs.
// A rows live in 6 bf16x8 registers (2 bins x rel rows 0..2), cndmask-selected
// per K-slice. V staged coalesced (R13-proven repack + rotation swizzle) with
// T14 split: next chunk's global loads issue BEFORE this chunk's MFMAs.
// C stored directly from accumulators (16B contiguous per lane, 4B-aligned).
__global__ __launch_bounds__(256) void roi_mfma_kernel(
    const unsigned int* __restrict__ Tw,   // channels-last bf16 viewed as u32
    const float* __restrict__ rois,
    float* __restrict__ out, int N)
{
    __shared__ __align__(16) short Vl[CG * 64];      // 16384 B

    int g   = blockIdx.x & (NXCD - 1);
    int n   = blockIdx.x >> 3;
    int tid = threadIdx.x;
    int wid = tid >> 6, lane = tid & 63, lane31 = lane & 31, hi = lane >> 5;

    const float* roi = rois + n * 5;
    int   b  = (int)roi[0];
    float x1 = roi[1] * SPATIAL_SCALE;
    float y1 = roi[2] * SPATIAL_SCALE;
    float x2 = roi[3] * SPATIAL_SCALE;
    float y2 = roi[4] * SPATIAL_SCALE;
    float bin_w = fmaxf(x2 - x1, 1.0f) * (1.0f / 7.0f);
    float bin_h = fmaxf(y2 - y1, 1.0f) * (1.0f / 7.0f);
    float hbw = 0.5f * bin_w, hbh = 0.5f * bin_h;
    float xq = x1 + 0.5f * hbw;              // xc0(pw) = pw*bin_w + xq
    float yq = y1 + 0.5f * hbh;

    // ---- uniform window base ----
    int minr = 48, maxr0 = 0, minc = 48;
    #pragma unroll
    for (int i = 0; i < 7; ++i) {
        float yc = fmaf((float)i, bin_h, yq);
        int yl = min(max((int)floorf(fminf(fmaxf(yc, 0.0f), 49.0f)), 0), 48);
        minr = min(minr, yl); maxr0 = max(maxr0, yl);
        float xc = fmaf((float)i, bin_w, xq);
        int xl = min(max((int)floorf(fminf(fmaxf(xc, 0.0f), 49.0f)), 0), 48);
        minc = min(minc, xl);
    }
    int rb = min(minr, 34);
    int cb = min(minc, 34) & ~1;             // even -> 4B-aligned staging
    int nch = ((min(maxr0 + 2, 49) - rb) >> 2) + 1;   // 1..4 chunks

    // ---- per-bin A-fragments for BOTH m-tiles (bins lane31, lane31+32) ----
    bf16x8 awA[3], awB[3];
    int ry0A, ry0B;
    #pragma unroll
    for (int mt = 0; mt < 2; ++mt) {
        int bin = mt * 32 + lane31;          // 0..63 (49..63 dummy)
        int ph = bin / 7;
        int pw = bin - ph * 7;
        float wr0, wr1, wr2; int yl0;
        {
            float c0 = fmaf((float)ph, bin_h, yq);
            float c1 = c0 + hbh;
            float v0 = (c0 >= -1.0f && c0 <= 50.0f) ? 1.0f : 0.0f;
            float v1 = (c1 >= -1.0f && c1 <= 50.0f) ? 1.0f : 0.0f;
            float cl0 = fminf(fmaxf(c0, 0.0f), 49.0f);
            float cl1 = fminf(fmaxf(c1, 0.0f), 49.0f);
            int l0 = min(max((int)floorf(cl0), 0), 48);
            int l1 = min(max((int)floorf(cl1), 0), 48);
            float f0 = cl0 - (float)l0, g0 = 1.0f - f0;
            float f1 = cl1 - (float)l1, g1 = 1.0f - f1;
            int dq = l1 - l0;
            wr0 = v0 * g0 + ((dq == 0) ? v1 * g1 : 0.0f);
            wr1 = v0 * f0 + ((dq == 0) ? v1 * f1 : v1 * g1);
            wr2 = (dq == 0) ? 0.0f : v1 * f1;
            yl0 = l0;
        }
        float u0, u1, u2; int xl0;
        {
            float c0 = fmaf((float)pw, bin_w, xq);
            float c1 = c0 + hbw;
            float v0 = (c0 >= -1.0f && c0 <= 50.0f) ? 1.0f : 0.0f;
            float v1 = (c1 >= -1.0f && c1 <= 50.0f) ? 1.0f : 0.0f;
            float cl0 = fminf(fmaxf(c0, 0.0f), 49.0f);
            float cl1 = fminf(fmaxf(c1, 0.0f), 49.0f);
            int l0 = min(max((int)floorf(cl0), 0), 48);
            int l1 = min(max((int)floorf(cl1), 0), 48);
            float f0 = cl0 - (float)l0, g0 = 1.0f - f0;
            float f1 = cl1 - (float)l1, g1 = 1.0f - f1;
            int dq = l1 - l0;
            u0 = v0 * g0 + ((dq == 0) ? v1 * g1 : 0.0f);
            u1 = v0 * f0 + ((dq == 0) ? v1 * f1 : v1 * g1);
            u2 = (dq == 0) ? 0.0f : v1 * f1;
            xl0 = l0;
        }
        int cc0 = xl0 - cb;
        bf16x8 a0, a1, a2;
        #pragma unroll
        for (int j = 0; j < 8; ++j) {
            int colj = hi * 8 + j;
            float uc = (colj == cc0) ? u0
                     : ((colj == cc0 + 1) ? u1 : ((colj == cc0 + 2) ? u2 : 0.0f));
            __hip_bfloat16 h0 = __float2bfloat16(wr0 * uc);
            __hip_bfloat16 h1 = __float2bfloat16(wr1 * uc);
            __hip_bfloat16 h2 = __float2bfloat16(wr2 * uc);
            a0[j] = *(short*)&h0;
            a1[j] = *(short*)&h1;
            a2[j] = *(short*)&h2;
        }
        if (mt == 0) { awA[0]=a0; awA[1]=a1; awA[2]=a2; ry0A = yl0 - rb; }
        else         { awB[0]=a0; awB[1]=a1; awB[2]=a2; ry0B = yl0 - rb; }
    }
    bf16x8 awz = {};

    // ---- MFMA main loop (T14 split staging, single Vl buffer) ----
    int ch0 = wid * 32 + lane31;             // this wave's N-tile ch (0..127)
    int rot0 = ch0 >> 2;
    int cq   = tid & 31;
    int half = (tid >> 5) & 1;
    int tg   = tid >> 6;
    int seg  = tg * 2 + half;
    int chA  = 4 * cq;
    int rotw = (seg + cq) & 7;
    const unsigned int* slabU = Tw + (size_t)(b * NXCD + g) * (HH * WW * 64);

    u2v A0, A1, A2, A3, A4, A5, A6, A7;
    {   // load chunk 0
        int r0 = rb + tg;
        const unsigned int* rp = slabU + (r0 * WW + cb + half * 8) * 64 + 2 * cq;
        A0 = *(const u2v*)(rp);       A1 = *(const u2v*)(rp + 64);
        A2 = *(const u2v*)(rp + 128); A3 = *(const u2v*)(rp + 192);
        A4 = *(const u2v*)(rp + 256); A5 = *(const u2v*)(rp + 320);
        A6 = *(const u2v*)(rp + 384); A7 = *(const u2v*)(rp + 448);
    }

    f32x16 acc0 = {}, acc1 = {};
    for (int chunk = 0; chunk < nch; ++chunk) {
        // repack current regs -> Vl
        u4v lo0, hi0, lo1, hi1;
        lo0[0] = (A0[0] & 0xffffu) | (A1[0] << 16);
        lo0[1] = (A2[0] & 0xffffu) | (A3[0] << 16);
        lo0[2] = (A4[0] & 0xffffu) | (A5[0] << 16);
        lo0[3] = (A6[0] & 0xffffu) | (A7[0] << 16);
        hi0[0] = (A0[0] >> 16) | (A1[0] & 0xffff0000u);
        hi0[1] = (A2[0] >> 16) | (A3[0] & 0xffff0000u);
        hi0[2] = (A4[0] >> 16) | (A5[0] & 0xffff0000u);
        hi0[3] = (A6[0] >> 16) | (A7[0] & 0xffff0000u);
        lo1[0] = (A0[1] & 0xffffu) | (A1[1] << 16);
        lo1[1] = (A2[1] & 0xffffu) | (A3[1] << 16);
        lo1[2] = (A4[1] & 0xffffu) | (A5[1] << 16);
        lo1[3] = (A6[1] & 0xffffu) | (A7[1] << 16);
        hi1[0] = (A0[1] >> 16) | (A1[1] & 0xffff0000u);
        hi1[1] = (A2[1] >> 16) | (A3[1] & 0xffff0000u);
        hi1[2] = (A4[1] >> 16) | (A5[1] & 0xffff0000u);
        hi1[3] = (A6[1] >> 16) | (A7[1] & 0xffff0000u);
        *(u4v*)&Vl[(chA    ) * 64 + rotw * 8] = lo0;
        *(u4v*)&Vl[(chA + 1) * 64 + rotw * 8] = hi0;
        *(u4v*)&Vl[(chA + 2) * 64 + rotw * 8] = lo1;
        *(u4v*)&Vl[(chA + 3) * 64 + rotw * 8] = hi1;
        __syncthreads();                     // Vl ready

        if (chunk + 1 < nch) {               // issue NEXT chunk's loads now;
            int r0 = rb + (chunk + 1) * 4 + tg;   // latency hides under MFMA
            const unsigned int* rp = slabU + (r0 * WW + cb + half * 8) * 64 + 2 * cq;
            A0 = *(const u2v*)(rp);       A1 = *(const u2v*)(rp + 64);
            A2 = *(const u2v*)(rp + 128); A3 = *(const u2v*)(rp + 192);
            A4 = *(const u2v*)(rp + 256); A5 = *(const u2v*)(rp + 320);
            A6 = *(const u2v*)(rp + 384); A7 = *(const u2v*)(rp + 448);
        }

        #pragma unroll
        for (int kl = 0; kl < 4; ++kl) {
            int kk = chunk * 4 + kl;
            bf16x8 bv = *(const bf16x8*)&Vl[ch0 * 64 + (((kl * 2 + hi) + rot0) & 7) * 8];
            int relA = kk - ry0A;
            int relB = kk - ry0B;
            bf16x8 avA = (relA == 0) ? awA[0]
                       : ((relA == 1) ? awA[1] : ((relA == 2) ? awA[2] : awz));
            bf16x8 avB = (relB == 0) ? awB[0]
                       : ((relB == 1) ? awB[1] : ((relB == 2) ? awB[2] : awz));
            acc0 = __builtin_amdgcn_mfma_f32_32x32x16_bf16(avA, bv, acc0, 0, 0, 0);
            acc1 = __builtin_amdgcn_mfma_f32_32x32x16_bf16(avB, bv, acc1, 0, 0, 0);
        }
        __syncthreads();                     // reads done before next ds_write
    }

    // ---- epilogue: direct stores from accumulators (x0.25 scale) ----
    // C layout: col(lane&31) = ch within N-tile; row = (reg&3)+8*(reg>>2)+4*hi.
    float* orow = out + (size_t)((n * C_TOTAL + g * CG) + ch0) * NPOS;
    #pragma unroll
    for (int q = 0; q < 4; ++q) {            // acc0: bins 0..31, all valid
        f4u v;
        v[0] = acc0[4*q]   * 0.25f;
        v[1] = acc0[4*q+1] * 0.25f;
        v[2] = acc0[4*q+2] * 0.25f;
        v[3] = acc0[4*q+3] * 0.25f;
        *(f4u*)(orow + 8 * q + 4 * hi) = v;
    }
    #pragma unroll
    for (int q = 0; q < 3; ++q) {            // acc1: bins 32..48
        int bin0 = 32 + 8 * q + 4 * hi;
        if (bin0 + 3 <= 48) {
            f4u v;
            v[0] = acc1[4*q]   * 0.25f;
            v[1] = acc1[4*q+1] * 0.25f;
            v[2] = acc1[4*q+2] * 0.25f;
            v[3] = acc1[4*q+3] * 0.25f;
            *(f4u*)(orow + bin0) = v;
        } else if (bin0 == 48) {
            orow[48] = acc1[4*q] * 0.25f;
        }
    }
}

// ---- Fallback (fp32 direct, ~R7) if workspace too small --------------------
__global__ __launch_bounds__(256) void roi_align_fallback(
    const float* __restrict__ data, const float* __restrict__ rois,
    float* __restrict__ out, int H, int W, int N)
{
    __shared__ __align__(16) float so[64 * NPOS];
    int i   = blockIdx.x;
    int xcd = i & (NXCD - 1);
    int j   = i >> 3;
    int scl = (j >= N) ? 1 : 0;
    int n   = j - scl * N;
    int superchunk = xcd * 2 + scl;
    int t = threadIdx.x;
    bool active = (t < 5 * NPOS);
    int tt = active ? t : 0;
    int s  = tt % NPOS;
    int g  = tt / NPOS;
    int cbase = g * 13;
    int cnt = (g < 4) ? 13 : 12;
    int pw = s % PW;
    int ph = s / PW;
    if (active) {
        const float* roi = rois + n * 5;
        int   b  = (int)roi[0];
        float x1 = roi[1] * SPATIAL_SCALE, y1 = roi[2] * SPATIAL_SCALE;
        float x2 = roi[3] * SPATIAL_SCALE, y2 = roi[4] * SPATIAL_SCALE;
        float roi_w = fmaxf(x2 - x1, 1.0f), roi_h = fmaxf(y2 - y1, 1.0f);
        float bin_w = roi_w * (1.0f / PW), bin_h = roi_h * (1.0f / PH);
        float xc0 = x1 + ((float)(pw * 2 + 0) + 0.5f) * bin_w * 0.5f;
        float xc1 = x1 + ((float)(pw * 2 + 1) + 0.5f) * bin_w * 0.5f;
        float vx0 = (xc0 >= -1.0f && xc0 <= (float)W) ? 1.0f : 0.0f;
        float vx1 = (xc1 >= -1.0f && xc1 <= (float)W) ? 1.0f : 0.0f;
        float xcl0 = fminf(fmaxf(xc0, 0.0f), (float)(W - 1));
        float xcl1 = fminf(fmaxf(xc1, 0.0f), (float)(W - 1));
        int xl0 = min(max((int)floorf(xcl0), 0), W - 2);
        int xl1 = min(max((int)floorf(xcl1), 0), W - 2);
        float lx0 = xcl0 - (float)xl0, hx0 = 1.0f - lx0;
        float lx1 = xcl1 - (float)xl1, hx1 = 1.0f - lx1;
        int xb = min(xl0 & ~1, W - 4);
        int p0 = xl0 - xb, p1 = xl1 - xb;
        float w4[4];
        #pragma unroll
        for (int k = 0; k < 4; ++k) {
            float a = (p0 == k) ? hx0 : ((p0 + 1 == k) ? lx0 : 0.0f);
            float c = (p1 == k) ? hx1 : ((p1 + 1 == k) ? lx1 : 0.0f);
            w4[k] = vx0 * a + vx1 * c;
        }
        float yc0 = y1 + ((float)(ph * 2 + 0) + 0.5f) * bin_h * 0.5f;
        float yc1 = y1 + ((float)(ph * 2 + 1) + 0.5f) * bin_h * 0.5f;
        float vy0 = (yc0 >= -1.0f && yc0 <= (float)H) ? 1.0f : 0.0f;
        float vy1 = (yc1 >= -1.0f && yc1 <= (float)H) ? 1.0f : 0.0f;
        float ycl0 = fminf(fmaxf(yc0, 0.0f), (float)(H - 1));
        float ycl1 = fminf(fmaxf(yc1, 0.0f), (float)(H - 1));
        int yl0 = min(max((int)floorf(ycl0), 0), H - 2);
        int yl1 = min(max((int)floorf(ycl1), 0), H - 2);
        float ly0 = ycl0 - (float)yl0, hy0 = 1.0f - ly0;
        float ly1 = ycl1 - (float)yl1, hy1 = 1.0f - ly1;
        float wy0 = 0.25f * vy0 * hy0, wy1 = 0.25f * vy0 * ly0;
        float wy2 = 0.25f * vy1 * hy1, wy3 = 0.25f * vy1 * ly1;
        int q = yl1 - yl0;
        float wr0 = wy0 + ((q == 0) ? wy2 : 0.0f);
        float wr1 = wy1 + ((q == 0) ? wy3 : wy2);
        float wr2 = (q == 0) ? 0.0f : wy3;
        int row0 = yl0;
        int row2 = min(yl0 + 2, H - 1);
        float wv[3][4];
        #pragma unroll
        for (int k = 0; k < 4; ++k) {
            wv[0][k] = wr0 * w4[k]; wv[1][k] = wr1 * w4[k]; wv[2][k] = wr2 * w4[k];
        }
        int c0 = superchunk * 64 + cbase;
        const int HW = H * W;
        unsigned slab = (unsigned)(b * C_TOTAL + c0) * (unsigned)HW;
        unsigned o0 = slab + (unsigned)(row0 * W + xb);
        unsigned o1 = o0 + (unsigned)W;
        unsigned o2 = slab + (unsigned)(row2 * W + xb);
        int ldsbase = cbase * NPOS + s;
        f4v a0 = *(const f4v*)(data + o0);
        f4v a1 = *(const f4v*)(data + o1);
        f4v a2 = *(const f4v*)(data + o2);
        int jj = 0;
        for (; jj < cnt - 1; ++jj) {
            o0 += HW; o1 += HW; o2 += HW;
            f4v b0 = *(const f4v*)(data + o0);
            f4v b1 = *(const f4v*)(data + o1);
            f4v b2 = *(const f4v*)(data + o2);
            float acc = wv[0][0]*a0.x + wv[0][1]*a0.y + wv[0][2]*a0.z + wv[0][3]*a0.w
                      + wv[1][0]*a1.x + wv[1][1]*a1.y + wv[1][2]*a1.z + wv[1][3]*a1.w
                      + wv[2][0]*a2.x + wv[2][1]*a2.y + wv[2][2]*a2.z + wv[2][3]*a2.w;
            so[ldsbase + jj * NPOS] = acc;
            a0 = b0; a1 = b1; a2 = b2;
        }
        float acc = wv[0][0]*a0.x + wv[0][1]*a0.y + wv[0][2]*a0.z + wv[0][3]*a0.w
                  + wv[1][0]*a1.x + wv[1][1]*a1.y + wv[1][2]*a1.z + wv[1][3]*a1.w
                  + wv[2][0]*a2.x + wv[2][1]*a2.y + wv[2][2]*a2.z + wv[2][3]*a2.w;
        so[ldsbase + jj * NPOS] = acc;
    }
    __syncthreads();
    unsigned base = (unsigned)(n * C_TOTAL + superchunk * 64) * NPOS;
    f4a* dst = (f4a*)(out + base);
    const f4a* src = (const f4a*)so;
    int tid = threadIdx.x;
    dst[tid] = src[tid];
    dst[256 + tid] = src[256 + tid];
    dst[512 + tid] = src[512 + tid];
    if (tid < 16) dst[768 + tid] = src[768 + tid];
}

extern "C" void kernel_launch(void* const* d_in, const int* in_sizes, int n_in,
                              void* d_out, int out_size, void* d_ws, size_t ws_size,
                              hipStream_t stream) {
    const float* data = (const float*)d_in[0];
    const float* rois = (const float*)d_in[1];
    float* out = (float*)d_out;
    const int N = in_sizes[1] / 5;

    if (ws_size >= TB_BYTES) {
        __hip_bfloat16* Tb = (__hip_bfloat16*)d_ws;
        transpose_bf16_kernel<<<2 * HH * NXCD, 256, 0, stream>>>(data, Tb);
        roi_mfma_kernel<<<N * NXCD, 256, 0, stream>>>(
            (const unsigned int*)d_ws, rois, out, N);
    } else {
        roi_align_fallback<<<N * 16, 256, 0, stream>>>(data, rois, out, HH, WW, N);
    }
}

// Round 16
// 47.625 us; speedup vs baseline: 1.0212x; 1.0212x over previous
//
#include <hip/hip_runtime.h>
#include <hip/hip_bf16.h>

#define SPATIAL_SCALE 0.0625f
#define PH 7
#define PW 7
#define C_TOTAL 1024
#define NXCD 8
#define NPOS 49
#define CG 128
#define HH 50
#define WW 50
#define TB_BYTES (2ULL * NXCD * HH * WW * CG * 2ULL)   // 10,240,000 B (bf16)

typedef short bf16x8 __attribute__((ext_vector_type(8)));
typedef float f32x16 __attribute__((ext_vector_type(16)));
typedef float f4a __attribute__((ext_vector_type(4), aligned(16)));
typedef float f4v __attribute__((ext_vector_type(4), aligned(8)));
typedef unsigned int u4v __attribute__((ext_vector_type(4), aligned(16)));
typedef unsigned int u2v __attribute__((ext_vector_type(2), aligned(8)));

// ---- Kernel 1: NCHW fp32 -> [b][g][y][x][c128] bf16 channels-last ----------
__global__ __launch_bounds__(256) void transpose_bf16_kernel(
    const float* __restrict__ in, __hip_bfloat16* __restrict__ Tb)
{
    __shared__ float lds[CG][WW + 1];
    int bid = blockIdx.x;            // (b*50 + y)*8 + g
    int g = bid & 7;
    int r = bid >> 3;
    int y = r % HH;
    int b = r / HH;
    int tid = threadIdx.x;

    const float* src = in + (size_t)(b * C_TOTAL + g * CG) * (HH * WW) + y * WW;
    #pragma unroll
    for (int it = 0; it < 25; ++it) {        // 6400 = 128c x 50x
        int idx = it * 256 + tid;
        int c = idx / WW;
        int x = idx - c * WW;
        lds[c][x] = src[c * (HH * WW) + x];
    }
    __syncthreads();
    __hip_bfloat16* dst = Tb + (size_t)((b * NXCD + g) * (HH * WW) + y * WW) * CG;
    #pragma unroll
    for (int it = 0; it < 25; ++it) {
        int idx = it * 256 + tid;
        int x = idx >> 7;                    // 0..49
        int c = idx & 127;
        dst[x * CG + c] = __float2bfloat16(lds[c][x]);
    }
}

// ---- Kernel 2: MFMA ROI align v4 ------------------------------------------
// Block = (roi n, slab g): 128 ch, 4 waves. blockIdx&7=g -> XCD pin.
// Tiling (R15): wave w = ONE N-tile (ch = w*32+lane31), TWO M-tiles per wave
// (bins lane31 / lane31+32) -> B ds_read ONCE per kl feeds 2 MFMAs.
// T14 split: next chunk's global loads issue before this chunk's MFMAs.
// Epilogue (R14, the proven one): 2 passes staging 64 ch through Vl-as-solh
// -> fully coalesced b128 global writes. (R15's direct stores = 196B-stride
// scatter = +5.5us; reverted.)
__global__ __launch_bounds__(256) void roi_mfma_kernel(
    const unsigned int* __restrict__ Tw,   // channels-last bf16 viewed as u32
    const float* __restrict__ rois,
    float* __restrict__ out, int N)
{
    __shared__ __align__(16) short Vl[CG * 64];      // 16384 B
    float* solh = (float*)Vl;                        // [64][52] f32 = 13312 B

    int g   = blockIdx.x & (NXCD - 1);
    int n   = blockIdx.x >> 3;
    int tid = threadIdx.x;
    int wid = tid >> 6, lane = tid & 63, lane31 = lane & 31, hi = lane >> 5;

    const float* roi = rois + n * 5;
    int   b  = (int)roi[0];
    float x1 = roi[1] * SPATIAL_SCALE;
    float y1 = roi[2] * SPATIAL_SCALE;
    float x2 = roi[3] * SPATIAL_SCALE;
    float y2 = roi[4] * SPATIAL_SCALE;
    float bin_w = fmaxf(x2 - x1, 1.0f) * (1.0f / 7.0f);
    float bin_h = fmaxf(y2 - y1, 1.0f) * (1.0f / 7.0f);
    float hbw = 0.5f * bin_w, hbh = 0.5f * bin_h;
    float xq = x1 + 0.5f * hbw;              // xc0(pw) = pw*bin_w + xq
    float yq = y1 + 0.5f * hbh;

    // ---- uniform window base ----
    int minr = 48, maxr0 = 0, minc = 48;
    #pragma unroll
    for (int i = 0; i < 7; ++i) {
        float yc = fmaf((float)i, bin_h, yq);
        int yl = min(max((int)floorf(fminf(fmaxf(yc, 0.0f), 49.0f)), 0), 48);
        minr = min(minr, yl); maxr0 = max(maxr0, yl);
        float xc = fmaf((float)i, bin_w, xq);
        int xl = min(max((int)floorf(fminf(fmaxf(xc, 0.0f), 49.0f)), 0), 48);
        minc = min(minc, xl);
    }
    int rb = min(minr, 34);
    int cb = min(minc, 34) & ~1;             // even -> 4B-aligned staging
    int nch = ((min(maxr0 + 2, 49) - rb) >> 2) + 1;   // 1..4 chunks

    // ---- per-bin A-fragments for BOTH m-tiles (bins lane31, lane31+32) ----
    bf16x8 awA[3], awB[3];
    int ry0A, ry0B;
    #pragma unroll
    for (int mt = 0; mt < 2; ++mt) {
        int bin = mt * 32 + lane31;          // 0..63 (49..63 dummy, not stored)
        int ph = bin / 7;
        int pw = bin - ph * 7;
        float wr0, wr1, wr2; int yl0;
        {
            float c0 = fmaf((float)ph, bin_h, yq);
            float c1 = c0 + hbh;
            float v0 = (c0 >= -1.0f && c0 <= 50.0f) ? 1.0f : 0.0f;
            float v1 = (c1 >= -1.0f && c1 <= 50.0f) ? 1.0f : 0.0f;
            float cl0 = fminf(fmaxf(c0, 0.0f), 49.0f);
            float cl1 = fminf(fmaxf(c1, 0.0f), 49.0f);
            int l0 = min(max((int)floorf(cl0), 0), 48);
            int l1 = min(max((int)floorf(cl1), 0), 48);
            float f0 = cl0 - (float)l0, g0 = 1.0f - f0;
            float f1 = cl1 - (float)l1, g1 = 1.0f - f1;
            int dq = l1 - l0;
            wr0 = v0 * g0 + ((dq == 0) ? v1 * g1 : 0.0f);
            wr1 = v0 * f0 + ((dq == 0) ? v1 * f1 : v1 * g1);
            wr2 = (dq == 0) ? 0.0f : v1 * f1;
            yl0 = l0;
        }
        float u0, u1, u2; int xl0;
        {
            float c0 = fmaf((float)pw, bin_w, xq);
            float c1 = c0 + hbw;
            float v0 = (c0 >= -1.0f && c0 <= 50.0f) ? 1.0f : 0.0f;
            float v1 = (c1 >= -1.0f && c1 <= 50.0f) ? 1.0f : 0.0f;
            float cl0 = fminf(fmaxf(c0, 0.0f), 49.0f);
            float cl1 = fminf(fmaxf(c1, 0.0f), 49.0f);
            int l0 = min(max((int)floorf(cl0), 0), 48);
            int l1 = min(max((int)floorf(cl1), 0), 48);
            float f0 = cl0 - (float)l0, g0 = 1.0f - f0;
            float f1 = cl1 - (float)l1, g1 = 1.0f - f1;
            int dq = l1 - l0;
            u0 = v0 * g0 + ((dq == 0) ? v1 * g1 : 0.0f);
            u1 = v0 * f0 + ((dq == 0) ? v1 * f1 : v1 * g1);
            u2 = (dq == 0) ? 0.0f : v1 * f1;
            xl0 = l0;
        }
        int cc0 = xl0 - cb;
        bf16x8 a0, a1, a2;
        #pragma unroll
        for (int j = 0; j < 8; ++j) {
            int colj = hi * 8 + j;
            float uc = (colj == cc0) ? u0
                     : ((colj == cc0 + 1) ? u1 : ((colj == cc0 + 2) ? u2 : 0.0f));
            __hip_bfloat16 h0 = __float2bfloat16(wr0 * uc);
            __hip_bfloat16 h1 = __float2bfloat16(wr1 * uc);
            __hip_bfloat16 h2 = __float2bfloat16(wr2 * uc);
            a0[j] = *(short*)&h0;
            a1[j] = *(short*)&h1;
            a2[j] = *(short*)&h2;
        }
        if (mt == 0) { awA[0]=a0; awA[1]=a1; awA[2]=a2; ry0A = yl0 - rb; }
        else         { awB[0]=a0; awB[1]=a1; awB[2]=a2; ry0B = yl0 - rb; }
    }
    bf16x8 awz = {};

    // ---- MFMA main loop (T14 split staging, single Vl buffer) ----
    int ch0 = wid * 32 + lane31;             // this wave's N-tile ch (0..127)
    int rot0 = ch0 >> 2;
    int cq   = tid & 31;
    int half = (tid >> 5) & 1;
    int tg   = tid >> 6;
    int chA  = 4 * cq;
    int rotw = ((tg * 2 + half) + cq) & 7;
    const unsigned int* slabU = Tw + (size_t)(b * NXCD + g) * (HH * WW * 64);

    u2v A0, A1, A2, A3, A4, A5, A6, A7;
    {   // load chunk 0
        int r0 = rb + tg;
        const unsigned int* rp = slabU + (r0 * WW + cb + half * 8) * 64 + 2 * cq;
        A0 = *(const u2v*)(rp);       A1 = *(const u2v*)(rp + 64);
        A2 = *(const u2v*)(rp + 128); A3 = *(const u2v*)(rp + 192);
        A4 = *(const u2v*)(rp + 256); A5 = *(const u2v*)(rp + 320);
        A6 = *(const u2v*)(rp + 384); A7 = *(const u2v*)(rp + 448);
    }

    f32x16 acc0 = {}, acc1 = {};
    for (int chunk = 0; chunk < nch; ++chunk) {
        // repack current regs -> Vl (rotation swizzle, R13-proven)
        u4v lo0, hi0, lo1, hi1;
        lo0[0] = (A0[0] & 0xffffu) | (A1[0] << 16);
        lo0[1] = (A2[0] & 0xffffu) | (A3[0] << 16);
        lo0[2] = (A4[0] & 0xffffu) | (A5[0] << 16);
        lo0[3] = (A6[0] & 0xffffu) | (A7[0] << 16);
        hi0[0] = (A0[0] >> 16) | (A1[0] & 0xffff0000u);
        hi0[1] = (A2[0] >> 16) | (A3[0] & 0xffff0000u);
        hi0[2] = (A4[0] >> 16) | (A5[0] & 0xffff0000u);
        hi0[3] = (A6[0] >> 16) | (A7[0] & 0xffff0000u);
        lo1[0] = (A0[1] & 0xffffu) | (A1[1] << 16);
        lo1[1] = (A2[1] & 0xffffu) | (A3[1] << 16);
        lo1[2] = (A4[1] & 0xffffu) | (A5[1] << 16);
        lo1[3] = (A6[1] & 0xffffu) | (A7[1] << 16);
        hi1[0] = (A0[1] >> 16) | (A1[1] & 0xffff0000u);
        hi1[1] = (A2[1] >> 16) | (A3[1] & 0xffff0000u);
        hi1[2] = (A4[1] >> 16) | (A5[1] & 0xffff0000u);
        hi1[3] = (A6[1] >> 16) | (A7[1] & 0xffff0000u);
        *(u4v*)&Vl[(chA    ) * 64 + rotw * 8] = lo0;
        *(u4v*)&Vl[(chA + 1) * 64 + rotw * 8] = hi0;
        *(u4v*)&Vl[(chA + 2) * 64 + rotw * 8] = lo1;
        *(u4v*)&Vl[(chA + 3) * 64 + rotw * 8] = hi1;
        __syncthreads();                     // Vl ready

        if (chunk + 1 < nch) {               // T14: issue NEXT chunk's loads;
            int r0 = rb + (chunk + 1) * 4 + tg;   // latency hides under MFMA
            const unsigned int* rp = slabU + (r0 * WW + cb + half * 8) * 64 + 2 * cq;
            A0 = *(const u2v*)(rp);       A1 = *(const u2v*)(rp + 64);
            A2 = *(const u2v*)(rp + 128); A3 = *(const u2v*)(rp + 192);
            A4 = *(const u2v*)(rp + 256); A5 = *(const u2v*)(rp + 320);
            A6 = *(const u2v*)(rp + 384); A7 = *(const u2v*)(rp + 448);
        }

        #pragma unroll
        for (int kl = 0; kl < 4; ++kl) {
            int kk = chunk * 4 + kl;
            bf16x8 bv = *(const bf16x8*)&Vl[ch0 * 64 + (((kl * 2 + hi) + rot0) & 7) * 8];
            int relA = kk - ry0A;
            int relB = kk - ry0B;
            bf16x8 avA = (relA == 0) ? awA[0]
                       : ((relA == 1) ? awA[1] : ((relA == 2) ? awA[2] : awz));
            bf16x8 avB = (relB == 0) ? awB[0]
                       : ((relB == 1) ? awB[1] : ((relB == 2) ? awB[2] : awz));
            acc0 = __builtin_amdgcn_mfma_f32_32x32x16_bf16(avA, bv, acc0, 0, 0, 0);
            acc1 = __builtin_amdgcn_mfma_f32_32x32x16_bf16(avB, bv, acc1, 0, 0, 0);
        }
        __syncthreads();                     // reads done before next ds_write
    }

    // ---- epilogue (R14-proven): 2 passes of 64 ch through Vl-as-solh ----
    int obase = (n * C_TOTAL + g * CG) * NPOS;
    int chloc = (wid & 1) * 32 + lane31;     // ch within this pass's 64-group

    #pragma unroll
    for (int p = 0; p < 2; ++p) {
        if ((wid >> 1) == p) {               // waves 2p,2p+1 own ch 64p..64p+63
            #pragma unroll
            for (int q = 0; q < 4; ++q) {    // acc0: bins 0..31
                int bin0 = 8 * q + 4 * hi;   // row = (reg&3)+8*(reg>>2)+4*hi
                f4a v;
                v[0] = acc0[4*q]; v[1] = acc0[4*q+1];
                v[2] = acc0[4*q+2]; v[3] = acc0[4*q+3];
                *(f4a*)&solh[chloc * 52 + bin0] = v;
            }
            #pragma unroll
            for (int q = 0; q < 4; ++q) {    // acc1: bins 32..48 (guarded)
                int bin0 = 32 + 8 * q + 4 * hi;
                if (bin0 <= 48) {
                    f4a v;
                    v[0] = acc1[4*q]; v[1] = acc1[4*q+1];
                    v[2] = acc1[4*q+2]; v[3] = acc1[4*q+3];
                    *(f4a*)&solh[chloc * 52 + bin0] = v;
                }
            }
        }
        __syncthreads();
        #pragma unroll
        for (int k2 = 0; k2 < 4; ++k2) {
            int t = k2 * 256 + tid;
            if (t < 784) {                   // 64*49/4
                f4a o;
                #pragma unroll
                for (int i2 = 0; i2 < 4; ++i2) {
                    int f = 4 * t + i2;
                    int fch = f / 49;
                    int fbin = f - fch * 49;
                    o[i2] = solh[fch * 52 + fbin] * 0.25f;
                }
                *(f4a*)(out + obase + p * 64 * NPOS + 4 * t) = o;
            }
        }
        __syncthreads();
    }
}

// ---- Fallback (fp32 direct, ~R7) if workspace too small --------------------
__global__ __launch_bounds__(256) void roi_align_fallback(
    const float* __restrict__ data, const float* __restrict__ rois,
    float* __restrict__ out, int H, int W, int N)
{
    __shared__ __align__(16) float so[64 * NPOS];
    int i   = blockIdx.x;
    int xcd = i & (NXCD - 1);
    int j   = i >> 3;
    int scl = (j >= N) ? 1 : 0;
    int n   = j - scl * N;
    int superchunk = xcd * 2 + scl;
    int t = threadIdx.x;
    bool active = (t < 5 * NPOS);
    int tt = active ? t : 0;
    int s  = tt % NPOS;
    int g  = tt / NPOS;
    int cbase = g * 13;
    int cnt = (g < 4) ? 13 : 12;
    int pw = s % PW;
    int ph = s / PW;
    if (active) {
        const float* roi = rois + n * 5;
        int   b  = (int)roi[0];
        float x1 = roi[1] * SPATIAL_SCALE, y1 = roi[2] * SPATIAL_SCALE;
        float x2 = roi[3] * SPATIAL_SCALE, y2 = roi[4] * SPATIAL_SCALE;
        float roi_w = fmaxf(x2 - x1, 1.0f), roi_h = fmaxf(y2 - y1, 1.0f);
        float bin_w = roi_w * (1.0f / PW), bin_h = roi_h * (1.0f / PH);
        float xc0 = x1 + ((float)(pw * 2 + 0) + 0.5f) * bin_w * 0.5f;
        float xc1 = x1 + ((float)(pw * 2 + 1) + 0.5f) * bin_w * 0.5f;
        float vx0 = (xc0 >= -1.0f && xc0 <= (float)W) ? 1.0f : 0.0f;
        float vx1 = (xc1 >= -1.0f && xc1 <= (float)W) ? 1.0f : 0.0f;
        float xcl0 = fminf(fmaxf(xc0, 0.0f), (float)(W - 1));
        float xcl1 = fminf(fmaxf(xc1, 0.0f), (float)(W - 1));
        int xl0 = min(max((int)floorf(xcl0), 0), W - 2);
        int xl1 = min(max((int)floorf(xcl1), 0), W - 2);
        float lx0 = xcl0 - (float)xl0, hx0 = 1.0f - lx0;
        float lx1 = xcl1 - (float)xl1, hx1 = 1.0f - lx1;
        int xb = min(xl0 & ~1, W - 4);
        int p0 = xl0 - xb, p1 = xl1 - xb;
        float w4[4];
        #pragma unroll
        for (int k = 0; k < 4; ++k) {
            float a = (p0 == k) ? hx0 : ((p0 + 1 == k) ? lx0 : 0.0f);
            float c = (p1 == k) ? hx1 : ((p1 + 1 == k) ? lx1 : 0.0f);
            w4[k] = vx0 * a + vx1 * c;
        }
        float yc0 = y1 + ((float)(ph * 2 + 0) + 0.5f) * bin_h * 0.5f;
        float yc1 = y1 + ((float)(ph * 2 + 1) + 0.5f) * bin_h * 0.5f;
        float vy0 = (yc0 >= -1.0f && yc0 <= (float)H) ? 1.0f : 0.0f;
        float vy1 = (yc1 >= -1.0f && yc1 <= (float)H) ? 1.0f : 0.0f;
        float ycl0 = fminf(fmaxf(yc0, 0.0f), (float)(H - 1));
        float ycl1 = fminf(fmaxf(yc1, 0.0f), (float)(H - 1));
        int yl0 = min(max((int)floorf(ycl0), 0), H - 2);
        int yl1 = min(max((int)floorf(ycl1), 0), H - 2);
        float ly0 = ycl0 - (float)yl0, hy0 = 1.0f - ly0;
        float ly1 = ycl1 - (float)yl1, hy1 = 1.0f - ly1;
        float wy0 = 0.25f * vy0 * hy0, wy1 = 0.25f * vy0 * ly0;
        float wy2 = 0.25f * vy1 * hy1, wy3 = 0.25f * vy1 * ly1;
        int q = yl1 - yl0;
        float wr0 = wy0 + ((q == 0) ? wy2 : 0.0f);
        float wr1 = wy1 + ((q == 0) ? wy3 : wy2);
        float wr2 = (q == 0) ? 0.0f : wy3;
        int row0 = yl0;
        int row2 = min(yl0 + 2, H - 1);
        float wv[3][4];
        #pragma unroll
        for (int k = 0; k < 4; ++k) {
            wv[0][k] = wr0 * w4[k]; wv[1][k] = wr1 * w4[k]; wv[2][k] = wr2 * w4[k];
        }
        int c0 = superchunk * 64 + cbase;
        const int HW = H * W;
        unsigned slab = (unsigned)(b * C_TOTAL + c0) * (unsigned)HW;
        unsigned o0 = slab + (unsigned)(row0 * W + xb);
        unsigned o1 = o0 + (unsigned)W;
        unsigned o2 = slab + (unsigned)(row2 * W + xb);
        int ldsbase = cbase * NPOS + s;
        f4v a0 = *(const f4v*)(data + o0);
        f4v a1 = *(const f4v*)(data + o1);
        f4v a2 = *(const f4v*)(data + o2);
        int jj = 0;
        for (; jj < cnt - 1; ++jj) {
            o0 += HW; o1 += HW; o2 += HW;
            f4v b0 = *(const f4v*)(data + o0);
            f4v b1 = *(const f4v*)(data + o1);
            f4v b2 = *(const f4v*)(data + o2);
            float acc = wv[0][0]*a0.x + wv[0][1]*a0.y + wv[0][2]*a0.z + wv[0][3]*a0.w
                      + wv[1][0]*a1.x + wv[1][1]*a1.y + wv[1][2]*a1.z + wv[1][3]*a1.w
                      + wv[2][0]*a2.x + wv[2][1]*a2.y + wv[2][2]*a2.z + wv[2][3]*a2.w;
            so[ldsbase + jj * NPOS] = acc;
            a0 = b0; a1 = b1; a2 = b2;
        }
        float acc = wv[0][0]*a0.x + wv[0][1]*a0.y + wv[0][2]*a0.z + wv[0][3]*a0.w
                  + wv[1][0]*a1.x + wv[1][1]*a1.y + wv[1][2]*a1.z + wv[1][3]*a1.w
                  + wv[2][0]*a2.x + wv[2][1]*a2.y + wv[2][2]*a2.z + wv[2][3]*a2.w;
        so[ldsbase + jj * NPOS] = acc;
    }
    __syncthreads();
    unsigned base = (unsigned)(n * C_TOTAL + superchunk * 64) * NPOS;
    f4a* dst = (f4a*)(out + base);
    const f4a* src = (const f4a*)so;
    int tid = threadIdx.x;
    dst[tid] = src[tid];
    dst[256 + tid] = src[256 + tid];
    dst[512 + tid] = src[512 + tid];
    if (tid < 16) dst[768 + tid] = src[768 + tid];
}

extern "C" void kernel_launch(void* const* d_in, const int* in_sizes, int n_in,
                              void* d_out, int out_size, void* d_ws, size_t ws_size,
                              hipStream_t stream) {
    const float* data = (const float*)d_in[0];
    const float* rois = (const float*)d_in[1];
    float* out = (float*)d_out;
    const int N = in_sizes[1] / 5;

    if (ws_size >= TB_BYTES) {
        __hip_bfloat16* Tb = (__hip_bfloat16*)d_ws;
        transpose_bf16_kernel<<<2 * HH * NXCD, 256, 0, stream>>>(data, Tb);
        roi_mfma_kernel<<<N * NXCD, 256, 0, stream>>>(
            (const unsigned int*)d_ws, rois, out, N);
    } else {
        roi_align_fallback<<<N * 16, 256, 0, stream>>>(data, rois, out, HH, WW, N);
    }
}

// Round 17
// 46.388 us; speedup vs baseline: 1.0485x; 1.0267x over previous
//
#include <hip/hip_runtime.h>
#include <hip/hip_bf16.h>

#define SPATIAL_SCALE 0.0625f
#define PH 7
#define PW 7
#define C_TOTAL 1024
#define NXCD 8
#define NPOS 49
#define CG 128
#define HH 50
#define WW 50
#define TB_BYTES (2ULL * NXCD * HH * WW * CG * 2ULL)   // 10,240,000 B (bf16)

typedef short bf16x8 __attribute__((ext_vector_type(8)));
typedef float f32x16 __attribute__((ext_vector_type(16)));
typedef float f4a __attribute__((ext_vector_type(4), aligned(16)));
typedef float f4v __attribute__((ext_vector_type(4), aligned(8)));
typedef unsigned int u4v __attribute__((ext_vector_type(4), aligned(16)));
typedef unsigned int u2v __attribute__((ext_vector_type(2), aligned(8)));

// ---- Kernel 0: per-ROI prep: window + per-bin bf16 A-fragments -------------
// 1 wave per ROI; thread t = bin (0..63; 49..63 dummy). Writes:
//   frag[roi][mt][hi][l31][row0..2][8]  bf16 (48B/lane, contiguous)
//   ry0t[roi][bin]  (yl0 - rb)
//   aux[roi] = {rb, cb, nch, batch}
// Weights pre-scaled by 0.25 (exact, pow2) -> epilogue store is raw acc.
__global__ __launch_bounds__(64) void roi_prep_kernel(
    const float* __restrict__ rois, short* __restrict__ frag,
    int* __restrict__ ry0t, int* __restrict__ aux, int N)
{
    int roi = blockIdx.x;
    int t   = threadIdx.x;

    const float* rp = rois + roi * 5;
    int   b  = (int)rp[0];
    float x1 = rp[1] * SPATIAL_SCALE;
    float y1 = rp[2] * SPATIAL_SCALE;
    float x2 = rp[3] * SPATIAL_SCALE;
    float y2 = rp[4] * SPATIAL_SCALE;
    float bin_w = fmaxf(x2 - x1, 1.0f) * (1.0f / 7.0f);
    float bin_h = fmaxf(y2 - y1, 1.0f) * (1.0f / 7.0f);
    float hbw = 0.5f * bin_w, hbh = 0.5f * bin_h;
    float xq = x1 + 0.5f * hbw;
    float yq = y1 + 0.5f * hbh;

    // window (all lanes, same result)
    int minr = 48, maxr0 = 0, minc = 48;
    #pragma unroll
    for (int i = 0; i < 7; ++i) {
        float yc = fmaf((float)i, bin_h, yq);
        int yl = min(max((int)floorf(fminf(fmaxf(yc, 0.0f), 49.0f)), 0), 48);
        minr = min(minr, yl); maxr0 = max(maxr0, yl);
        float xc = fmaf((float)i, bin_w, xq);
        int xl = min(max((int)floorf(fminf(fmaxf(xc, 0.0f), 49.0f)), 0), 48);
        minc = min(minc, xl);
    }
    int rb = min(minr, 34);
    int cb = min(minc, 34) & ~1;
    int nch = ((min(maxr0 + 2, 49) - rb) >> 2) + 1;
    if (t == 0) {
        aux[roi * 4 + 0] = rb;
        aux[roi * 4 + 1] = cb;
        aux[roi * 4 + 2] = nch;
        aux[roi * 4 + 3] = b;
    }

    // per-bin params (identical math to R14)
    int ph = t / 7;
    int pw = t - ph * 7;
    float wr0, wr1, wr2; int yl0;
    {
        float c0 = fmaf((float)ph, bin_h, yq);
        float c1 = c0 + hbh;
        float v0 = (c0 >= -1.0f && c0 <= 50.0f) ? 1.0f : 0.0f;
        float v1 = (c1 >= -1.0f && c1 <= 50.0f) ? 1.0f : 0.0f;
        float cl0 = fminf(fmaxf(c0, 0.0f), 49.0f);
        float cl1 = fminf(fmaxf(c1, 0.0f), 49.0f);
        int l0 = min(max((int)floorf(cl0), 0), 48);
        int l1 = min(max((int)floorf(cl1), 0), 48);
        float f0 = cl0 - (float)l0, g0 = 1.0f - f0;
        float f1 = cl1 - (float)l1, g1 = 1.0f - f1;
        int dq = l1 - l0;
        wr0 = v0 * g0 + ((dq == 0) ? v1 * g1 : 0.0f);
        wr1 = v0 * f0 + ((dq == 0) ? v1 * f1 : v1 * g1);
        wr2 = (dq == 0) ? 0.0f : v1 * f1;
        yl0 = l0;
    }
    float u0, u1, u2; int xl0;
    {
        float c0 = fmaf((float)pw, bin_w, xq);
        float c1 = c0 + hbw;
        float v0 = (c0 >= -1.0f && c0 <= 50.0f) ? 1.0f : 0.0f;
        float v1 = (c1 >= -1.0f && c1 <= 50.0f) ? 1.0f : 0.0f;
        float cl0 = fminf(fmaxf(c0, 0.0f), 49.0f);
        float cl1 = fminf(fmaxf(c1, 0.0f), 49.0f);
        int l0 = min(max((int)floorf(cl0), 0), 48);
        int l1 = min(max((int)floorf(cl1), 0), 48);
        float f0 = cl0 - (float)l0, g0 = 1.0f - f0;
        float f1 = cl1 - (float)l1, g1 = 1.0f - f1;
        int dq = l1 - l0;
        u0 = v0 * g0 + ((dq == 0) ? v1 * g1 : 0.0f);
        u1 = v0 * f0 + ((dq == 0) ? v1 * f1 : v1 * g1);
        u2 = (dq == 0) ? 0.0f : v1 * f1;
        xl0 = l0;
    }
    ry0t[roi * 64 + t] = yl0 - rb;
    int cc0 = xl0 - cb;

    float wrr[3] = { 0.25f * wr0, 0.25f * wr1, 0.25f * wr2 };
    int mt  = t >> 5;
    int l31 = t & 31;
    #pragma unroll
    for (int hi2 = 0; hi2 < 2; ++hi2) {
        bf16x8 row[3];
        #pragma unroll
        for (int r = 0; r < 3; ++r) {
            #pragma unroll
            for (int j = 0; j < 8; ++j) {
                int c = hi2 * 8 + j;
                float uc = (c == cc0) ? u0
                         : ((c == cc0 + 1) ? u1 : ((c == cc0 + 2) ? u2 : 0.0f));
                __hip_bfloat16 h = __float2bfloat16(wrr[r] * uc);
                row[r][j] = *(short*)&h;
            }
        }
        short* dst = frag + ((((size_t)roi * 2 + mt) * 2 + hi2) * 32 + l31) * 24;
        *(bf16x8*)(dst)      = row[0];
        *(bf16x8*)(dst + 8)  = row[1];
        *(bf16x8*)(dst + 16) = row[2];
    }
}

// ---- Kernel 1: NCHW fp32 -> [b][g][y][x][c128] bf16 channels-last ----------
__global__ __launch_bounds__(256) void transpose_bf16_kernel(
    const float* __restrict__ in, __hip_bfloat16* __restrict__ Tb)
{
    __shared__ float lds[CG][WW + 1];
    int bid = blockIdx.x;            // (b*50 + y)*8 + g
    int g = bid & 7;
    int r = bid >> 3;
    int y = r % HH;
    int b = r / HH;
    int tid = threadIdx.x;

    const float* src = in + (size_t)(b * C_TOTAL + g * CG) * (HH * WW) + y * WW;
    #pragma unroll
    for (int it = 0; it < 25; ++it) {        // 6400 = 128c x 50x
        int idx = it * 256 + tid;
        int c = idx / WW;
        int x = idx - c * WW;
        lds[c][x] = src[c * (HH * WW) + x];
    }
    __syncthreads();
    __hip_bfloat16* dst = Tb + (size_t)((b * NXCD + g) * (HH * WW) + y * WW) * CG;
    #pragma unroll
    for (int it = 0; it < 25; ++it) {
        int idx = it * 256 + tid;
        int x = idx >> 7;                    // 0..49
        int c = idx & 127;
        dst[x * CG + c] = __float2bfloat16(lds[c][x]);
    }
}

// ---- Kernel 2: MFMA ROI align v5 = R14 main loop + table-fed preamble ------
// Block = (roi n, slab g): 128 ch, 4 waves. blockIdx&7=g -> XCD pin.
// Wave (m=wid>>1, nt=wid&1): A = bins m*32+lane31 (3 bf16x8 regs, LOADED from
// frag table, cndmask-selected per K-slice), B = ch {nt*32, +64} (2 ds_reads),
// 2 accumulators. V staged coalesced (repack + rotation swizzle). Epilogue:
// R14's 2-pass solh staging -> coalesced b128 writes (0.25 pre-baked).
__global__ __launch_bounds__(256) void roi_mfma_kernel(
    const unsigned int* __restrict__ Tw,
    const short* __restrict__ frag,
    const int* __restrict__ ry0t,
    const int* __restrict__ aux,
    float* __restrict__ out, int N)
{
    __shared__ __align__(16) short Vl[CG * 64];      // 16384 B
    float* solh = (float*)Vl;                        // [64][52] f32 reuse

    int g   = blockIdx.x & (NXCD - 1);
    int n   = blockIdx.x >> 3;
    int tid = threadIdx.x;
    int wid = tid >> 6, lane = tid & 63, lane31 = lane & 31, hi = lane >> 5;

    // ---- table loads (issue early; all coalesced / broadcast) ----
    int m   = wid >> 1;
    int bin = m * 32 + lane31;
    const short* fb = frag + ((((size_t)n * 2 + m) * 2 + hi) * 32 + lane31) * 24;
    bf16x8 aw0 = *(const bf16x8*)(fb);
    bf16x8 aw1 = *(const bf16x8*)(fb + 8);
    bf16x8 aw2 = *(const bf16x8*)(fb + 16);
    int ry0 = ry0t[n * 64 + bin];
    int rb  = aux[n * 4 + 0];
    int cb  = aux[n * 4 + 1];
    int nch = aux[n * 4 + 2];
    int b   = aux[n * 4 + 3];
    bf16x8 awz = {};

    // ---- main loop (R14-proven structure) ----
    int ch0 = (wid & 1) * 32 + lane31;       // N-tile pair {ch0, ch0+64}
    int ch1 = ch0 + 64;
    int rot0 = ch0 >> 2, rot1 = ch1 >> 2;
    int cq   = tid & 31;
    int half = (tid >> 5) & 1;
    int tg   = tid >> 6;
    int chA  = 4 * cq;
    int rotw = ((tg * 2 + half) + cq) & 7;
    const unsigned int* slabU = Tw + (size_t)(b * NXCD + g) * (HH * WW * 64);

    f32x16 acc0 = {}, acc1 = {};
    for (int chunk = 0; chunk < nch; ++chunk) {
        int r0 = rb + chunk * 4 + tg;        // <= 49 always (rb<=34)
        const unsigned int* rp = slabU + (r0 * WW + cb + half * 8) * 64 + 2 * cq;
        u2v A0 = *(const u2v*)(rp);       u2v A1 = *(const u2v*)(rp + 64);
        u2v A2 = *(const u2v*)(rp + 128); u2v A3 = *(const u2v*)(rp + 192);
        u2v A4 = *(const u2v*)(rp + 256); u2v A5 = *(const u2v*)(rp + 320);
        u2v A6 = *(const u2v*)(rp + 384); u2v A7 = *(const u2v*)(rp + 448);
        u4v lo0, hi0, lo1, hi1;
        lo0[0] = (A0[0] & 0xffffu) | (A1[0] << 16);
        lo0[1] = (A2[0] & 0xffffu) | (A3[0] << 16);
        lo0[2] = (A4[0] & 0xffffu) | (A5[0] << 16);
        lo0[3] = (A6[0] & 0xffffu) | (A7[0] << 16);
        hi0[0] = (A0[0] >> 16) | (A1[0] & 0xffff0000u);
        hi0[1] = (A2[0] >> 16) | (A3[0] & 0xffff0000u);
        hi0[2] = (A4[0] >> 16) | (A5[0] & 0xffff0000u);
        hi0[3] = (A6[0] >> 16) | (A7[0] & 0xffff0000u);
        lo1[0] = (A0[1] & 0xffffu) | (A1[1] << 16);
        lo1[1] = (A2[1] & 0xffffu) | (A3[1] << 16);
        lo1[2] = (A4[1] & 0xffffu) | (A5[1] << 16);
        lo1[3] = (A6[1] & 0xffffu) | (A7[1] << 16);
        hi1[0] = (A0[1] >> 16) | (A1[1] & 0xffff0000u);
        hi1[1] = (A2[1] >> 16) | (A3[1] & 0xffff0000u);
        hi1[2] = (A4[1] >> 16) | (A5[1] & 0xffff0000u);
        hi1[3] = (A6[1] >> 16) | (A7[1] & 0xffff0000u);
        *(u4v*)&Vl[(chA    ) * 64 + rotw * 8] = lo0;
        *(u4v*)&Vl[(chA + 1) * 64 + rotw * 8] = hi0;
        *(u4v*)&Vl[(chA + 2) * 64 + rotw * 8] = lo1;
        *(u4v*)&Vl[(chA + 3) * 64 + rotw * 8] = hi1;
        __syncthreads();

        #pragma unroll
        for (int kl = 0; kl < 4; ++kl) {
            int kk = chunk * 4 + kl;
            int rel = kk - ry0;
            bf16x8 av = (rel == 0) ? aw0
                      : ((rel == 1) ? aw1 : ((rel == 2) ? aw2 : awz));
            bf16x8 bv0 = *(const bf16x8*)&Vl[ch0 * 64 + (((kl * 2 + hi) + rot0) & 7) * 8];
            bf16x8 bv1 = *(const bf16x8*)&Vl[ch1 * 64 + (((kl * 2 + hi) + rot1) & 7) * 8];
            acc0 = __builtin_amdgcn_mfma_f32_32x32x16_bf16(av, bv0, acc0, 0, 0, 0);
            acc1 = __builtin_amdgcn_mfma_f32_32x32x16_bf16(av, bv1, acc1, 0, 0, 0);
        }
        __syncthreads();
    }

    // ---- epilogue (R14-proven): 2 passes of 64 ch through Vl-as-solh ----
    int obase = (n * C_TOTAL + g * CG) * NPOS;
    #pragma unroll
    for (int q = 0; q < 4; ++q) {            // pass 0: acc0, ch 0..63
        int bin0 = m * 32 + 8 * q + 4 * hi;
        if (bin0 <= 48) {
            f4a v;
            v[0] = acc0[4*q]; v[1] = acc0[4*q+1];
            v[2] = acc0[4*q+2]; v[3] = acc0[4*q+3];
            *(f4a*)&solh[ch0 * 52 + bin0] = v;
        }
    }
    __syncthreads();
    #pragma unroll
    for (int k2 = 0; k2 < 4; ++k2) {
        int t = k2 * 256 + tid;
        if (t < 784) {
            f4a o;
            #pragma unroll
            for (int i2 = 0; i2 < 4; ++i2) {
                int f = 4 * t + i2;
                int fch = f / 49;
                int fbin = f - fch * 49;
                o[i2] = solh[fch * 52 + fbin];
            }
            *(f4a*)(out + obase + 4 * t) = o;
        }
    }
    __syncthreads();
    #pragma unroll
    for (int q = 0; q < 4; ++q) {            // pass 1: acc1, ch 64..127
        int bin0 = m * 32 + 8 * q + 4 * hi;
        if (bin0 <= 48) {
            f4a v;
            v[0] = acc1[4*q]; v[1] = acc1[4*q+1];
            v[2] = acc1[4*q+2]; v[3] = acc1[4*q+3];
            *(f4a*)&solh[ch0 * 52 + bin0] = v;
        }
    }
    __syncthreads();
    #pragma unroll
    for (int k2 = 0; k2 < 4; ++k2) {
        int t = k2 * 256 + tid;
        if (t < 784) {
            f4a o;
            #pragma unroll
            for (int i2 = 0; i2 < 4; ++i2) {
                int f = 4 * t + i2;
                int fch = f / 49;
                int fbin = f - fch * 49;
                o[i2] = solh[fch * 52 + fbin];
            }
            *(f4a*)(out + obase + 64 * NPOS + 4 * t) = o;
        }
    }
}

// ---- Fallback (fp32 direct, ~R7) if workspace too small --------------------
__global__ __launch_bounds__(256) void roi_align_fallback(
    const float* __restrict__ data, const float* __restrict__ rois,
    float* __restrict__ out, int H, int W, int N)
{
    __shared__ __align__(16) float so[64 * NPOS];
    int i   = blockIdx.x;
    int xcd = i & (NXCD - 1);
    int j   = i >> 3;
    int scl = (j >= N) ? 1 : 0;
    int n   = j - scl * N;
    int superchunk = xcd * 2 + scl;
    int t = threadIdx.x;
    bool active = (t < 5 * NPOS);
    int tt = active ? t : 0;
    int s  = tt % NPOS;
    int g  = tt / NPOS;
    int cbase = g * 13;
    int cnt = (g < 4) ? 13 : 12;
    int pw = s % PW;
    int ph = s / PW;
    if (active) {
        const float* roi = rois + n * 5;
        int   b  = (int)roi[0];
        float x1 = roi[1] * SPATIAL_SCALE, y1 = roi[2] * SPATIAL_SCALE;
        float x2 = roi[3] * SPATIAL_SCALE, y2 = roi[4] * SPATIAL_SCALE;
        float roi_w = fmaxf(x2 - x1, 1.0f), roi_h = fmaxf(y2 - y1, 1.0f);
        float bin_w = roi_w * (1.0f / PW), bin_h = roi_h * (1.0f / PH);
        float xc0 = x1 + ((float)(pw * 2 + 0) + 0.5f) * bin_w * 0.5f;
        float xc1 = x1 + ((float)(pw * 2 + 1) + 0.5f) * bin_w * 0.5f;
        float vx0 = (xc0 >= -1.0f && xc0 <= (float)W) ? 1.0f : 0.0f;
        float vx1 = (xc1 >= -1.0f && xc1 <= (float)W) ? 1.0f : 0.0f;
        float xcl0 = fminf(fmaxf(xc0, 0.0f), (float)(W - 1));
        float xcl1 = fminf(fmaxf(xc1, 0.0f), (float)(W - 1));
        int xl0 = min(max((int)floorf(xcl0), 0), W - 2);
        int xl1 = min(max((int)floorf(xcl1), 0), W - 2);
        float lx0 = xcl0 - (float)xl0, hx0 = 1.0f - lx0;
        float lx1 = xcl1 - (float)xl1, hx1 = 1.0f - lx1;
        int xb = min(xl0 & ~1, W - 4);
        int p0 = xl0 - xb, p1 = xl1 - xb;
        float w4[4];
        #pragma unroll
        for (int k = 0; k < 4; ++k) {
            float a = (p0 == k) ? hx0 : ((p0 + 1 == k) ? lx0 : 0.0f);
            float c = (p1 == k) ? hx1 : ((p1 + 1 == k) ? lx1 : 0.0f);
            w4[k] = vx0 * a + vx1 * c;
        }
        float yc0 = y1 + ((float)(ph * 2 + 0) + 0.5f) * bin_h * 0.5f;
        float yc1 = y1 + ((float)(ph * 2 + 1) + 0.5f) * bin_h * 0.5f;
        float vy0 = (yc0 >= -1.0f && yc0 <= (float)H) ? 1.0f : 0.0f;
        float vy1 = (yc1 >= -1.0f && yc1 <= (float)H) ? 1.0f : 0.0f;
        float ycl0 = fminf(fmaxf(yc0, 0.0f), (float)(H - 1));
        float ycl1 = fminf(fmaxf(yc1, 0.0f), (float)(H - 1));
        int yl0 = min(max((int)floorf(ycl0), 0), H - 2);
        int yl1 = min(max((int)floorf(ycl1), 0), H - 2);
        float ly0 = ycl0 - (float)yl0, hy0 = 1.0f - ly0;
        float ly1 = ycl1 - (float)yl1, hy1 = 1.0f - ly1;
        float wy0 = 0.25f * vy0 * hy0, wy1 = 0.25f * vy0 * ly0;
        float wy2 = 0.25f * vy1 * hy1, wy3 = 0.25f * vy1 * ly1;
        int q = yl1 - yl0;
        float wr0 = wy0 + ((q == 0) ? wy2 : 0.0f);
        float wr1 = wy1 + ((q == 0) ? wy3 : wy2);
        float wr2 = (q == 0) ? 0.0f : wy3;
        int row0 = yl0;
        int row2 = min(yl0 + 2, H - 1);
        float wv[3][4];
        #pragma unroll
        for (int k = 0; k < 4; ++k) {
            wv[0][k] = wr0 * w4[k]; wv[1][k] = wr1 * w4[k]; wv[2][k] = wr2 * w4[k];
        }
        int c0 = superchunk * 64 + cbase;
        const int HW = H * W;
        unsigned slab = (unsigned)(b * C_TOTAL + c0) * (unsigned)HW;
        unsigned o0 = slab + (unsigned)(row0 * W + xb);
        unsigned o1 = o0 + (unsigned)W;
        unsigned o2 = slab + (unsigned)(row2 * W + xb);
        int ldsbase = cbase * NPOS + s;
        f4v a0 = *(const f4v*)(data + o0);
        f4v a1 = *(const f4v*)(data + o1);
        f4v a2 = *(const f4v*)(data + o2);
        int jj = 0;
        for (; jj < cnt - 1; ++jj) {
            o0 += HW; o1 += HW; o2 += HW;
            f4v b0 = *(const f4v*)(data + o0);
            f4v b1 = *(const f4v*)(data + o1);
            f4v b2 = *(const f4v*)(data + o2);
            float acc = wv[0][0]*a0.x + wv[0][1]*a0.y + wv[0][2]*a0.z + wv[0][3]*a0.w
                      + wv[1][0]*a1.x + wv[1][1]*a1.y + wv[1][2]*a1.z + wv[1][3]*a1.w
                      + wv[2][0]*a2.x + wv[2][1]*a2.y + wv[2][2]*a2.z + wv[2][3]*a2.w;
            so[ldsbase + jj * NPOS] = acc;
            a0 = b0; a1 = b1; a2 = b2;
        }
        float acc = wv[0][0]*a0.x + wv[0][1]*a0.y + wv[0][2]*a0.z + wv[0][3]*a0.w
                  + wv[1][0]*a1.x + wv[1][1]*a1.y + wv[1][2]*a1.z + wv[1][3]*a1.w
                  + wv[2][0]*a2.x + wv[2][1]*a2.y + wv[2][2]*a2.z + wv[2][3]*a2.w;
        so[ldsbase + jj * NPOS] = acc;
    }
    __syncthreads();
    unsigned base = (unsigned)(n * C_TOTAL + superchunk * 64) * NPOS;
    f4a* dst = (f4a*)(out + base);
    const f4a* src = (const f4a*)so;
    int tid = threadIdx.x;
    dst[tid] = src[tid];
    dst[256 + tid] = src[256 + tid];
    dst[512 + tid] = src[512 + tid];
    if (tid < 16) dst[768 + tid] = src[768 + tid];
}

extern "C" void kernel_launch(void* const* d_in, const int* in_sizes, int n_in,
                              void* d_out, int out_size, void* d_ws, size_t ws_size,
                              hipStream_t stream) {
    const float* data = (const float*)d_in[0];
    const float* rois = (const float*)d_in[1];
    float* out = (float*)d_out;
    const int N = in_sizes[1] / 5;

    size_t frag_off  = TB_BYTES;
    size_t frag_bytes = (size_t)N * 2 * 2 * 32 * 24 * 2;   // 6144 B / roi
    size_t ry0_off   = frag_off + frag_bytes;
    size_t aux_off   = ry0_off + (size_t)N * 64 * 4;
    size_t need      = aux_off + (size_t)N * 4 * 4;

    if (ws_size >= need) {
        char* ws = (char*)d_ws;
        __hip_bfloat16* Tb = (__hip_bfloat16*)ws;
        short* frag = (short*)(ws + frag_off);
        int*   ry0t = (int*)(ws + ry0_off);
        int*   aux  = (int*)(ws + aux_off);
        roi_prep_kernel<<<N, 64, 0, stream>>>(rois, frag, ry0t, aux, N);
        transpose_bf16_kernel<<<2 * HH * NXCD, 256, 0, stream>>>(data, Tb);
        roi_mfma_kernel<<<N * NXCD, 256, 0, stream>>>(
            (const unsigned int*)ws, frag, ry0t, aux, out, N);
    } else {
        roi_align_fallback<<<N * 16, 256, 0, stream>>>(data, rois, out, HH, WW, N);
    }
}

// Round 18
// 43.676 us; speedup vs baseline: 1.1136x; 1.0621x over previous
//
#include <hip/hip_runtime.h>
#include <hip/hip_bf16.h>

#define SPATIAL_SCALE 0.0625f
#define PH 7
#define PW 7
#define C_TOTAL 1024
#define NXCD 8
#define NPOS 49
#define CG 128
#define HH 50
#define WW 50
#define TB_BYTES (2ULL * NXCD * HH * WW * CG * 2ULL)   // 10,240,000 B (bf16)

typedef short bf16x8 __attribute__((ext_vector_type(8)));
typedef float f32x16 __attribute__((ext_vector_type(16)));
typedef float f4a __attribute__((ext_vector_type(4), aligned(16)));
typedef float f4v __attribute__((ext_vector_type(4), aligned(8)));
typedef unsigned int u4v __attribute__((ext_vector_type(4), aligned(16)));
typedef unsigned int u2v __attribute__((ext_vector_type(2), aligned(8)));

// ---- Kernel 1: NCHW fp32 -> [b][g][y][x][c128] bf16 channels-last ----------
__global__ __launch_bounds__(256) void transpose_bf16_kernel(
    const float* __restrict__ in, __hip_bfloat16* __restrict__ Tb)
{
    __shared__ float lds[CG][WW + 1];
    int bid = blockIdx.x;            // (b*50 + y)*8 + g
    int g = bid & 7;
    int r = bid >> 3;
    int y = r % HH;
    int b = r / HH;
    int tid = threadIdx.x;

    const float* src = in + (size_t)(b * C_TOTAL + g * CG) * (HH * WW) + y * WW;
    #pragma unroll
    for (int it = 0; it < 25; ++it) {        // 6400 = 128c x 50x
        int idx = it * 256 + tid;
        int c = idx / WW;
        int x = idx - c * WW;
        lds[c][x] = src[c * (HH * WW) + x];
    }
    __syncthreads();
    __hip_bfloat16* dst = Tb + (size_t)((b * NXCD + g) * (HH * WW) + y * WW) * CG;
    #pragma unroll
    for (int it = 0; it < 25; ++it) {
        int idx = it * 256 + tid;
        int x = idx >> 7;                    // 0..49
        int c = idx & 127;
        dst[x * CG + c] = __float2bfloat16(lds[c][x]);
    }
}

// ---- Kernel 2: MFMA ROI align (R14 structure + VGPR-neutral load schedule) -
// Block = (roi n, slab g): 128 ch, 4 waves. blockIdx&7=g -> XCD pin.
// Wave (m=wid>>1, nt=wid&1): A = bin m*32+lane31 (3 bf16x8 regs, built from
// per-lane params, cndmask-selected per K-slice), B = ch {nt*32, +64}
// (2 ds_reads/kl), 2 accumulators. Changes vs R14 (both zero peak-VGPR):
//   1. chunk-0 global loads issued BEFORE the A-fragment build (L2 latency
//      hides under ~150 VALU preamble).
//   2. loop reordered repack -> ds_write -> barrier -> load(c+1, reusing the
//      same A regs) -> MFMA -> barrier (load latency hides under MFMA).
__global__ __launch_bounds__(256) void roi_mfma_kernel(
    const unsigned int* __restrict__ Tw,   // channels-last bf16 viewed as u32
    const float* __restrict__ rois,
    float* __restrict__ out, int N)
{
    __shared__ __align__(16) short Vl[CG * 64];      // 16384 B
    float* solh = (float*)Vl;                        // [64][52] f32 reuse

    int g   = blockIdx.x & (NXCD - 1);
    int n   = blockIdx.x >> 3;
    int tid = threadIdx.x;
    int wid = tid >> 6, lane = tid & 63, lane31 = lane & 31, hi = lane >> 5;

    const float* roi = rois + n * 5;
    int   b  = (int)roi[0];
    float x1 = roi[1] * SPATIAL_SCALE;
    float y1 = roi[2] * SPATIAL_SCALE;
    float x2 = roi[3] * SPATIAL_SCALE;
    float y2 = roi[4] * SPATIAL_SCALE;
    float bin_w = fmaxf(x2 - x1, 1.0f) * (1.0f / 7.0f);
    float bin_h = fmaxf(y2 - y1, 1.0f) * (1.0f / 7.0f);
    float hbw = 0.5f * bin_w, hbh = 0.5f * bin_h;
    float xq = x1 + 0.5f * hbw;              // xc0(pw) = pw*bin_w + xq
    float yq = y1 + 0.5f * hbh;

    // ---- uniform window base ----
    int minr = 48, maxr0 = 0, minc = 48;
    #pragma unroll
    for (int i = 0; i < 7; ++i) {
        float yc = fmaf((float)i, bin_h, yq);
        int yl = min(max((int)floorf(fminf(fmaxf(yc, 0.0f), 49.0f)), 0), 48);
        minr = min(minr, yl); maxr0 = max(maxr0, yl);
        float xc = fmaf((float)i, bin_w, xq);
        int xl = min(max((int)floorf(fminf(fmaxf(xc, 0.0f), 49.0f)), 0), 48);
        minc = min(minc, xl);
    }
    int rb = min(minr, 34);
    int cb = min(minc, 34) & ~1;             // even -> 4B-aligned staging
    int nch = ((min(maxr0 + 2, 49) - rb) >> 2) + 1;   // 1..4 chunks

    // ---- chunk-0 loads issued NOW (latency hides under preamble below) ----
    int cq   = tid & 31;
    int half = (tid >> 5) & 1;
    int tg   = tid >> 6;
    int chA  = 4 * cq;
    int rotw = ((tg * 2 + half) + cq) & 7;
    const unsigned int* slabU = Tw + (size_t)(b * NXCD + g) * (HH * WW * 64);

    u2v A0, A1, A2, A3, A4, A5, A6, A7;
    {
        int r0 = rb + tg;
        const unsigned int* rp = slabU + (r0 * WW + cb + half * 8) * 64 + 2 * cq;
        A0 = *(const u2v*)(rp);       A1 = *(const u2v*)(rp + 64);
        A2 = *(const u2v*)(rp + 128); A3 = *(const u2v*)(rp + 192);
        A4 = *(const u2v*)(rp + 256); A5 = *(const u2v*)(rp + 320);
        A6 = *(const u2v*)(rp + 384); A7 = *(const u2v*)(rp + 448);
    }

    // ---- own-bin params (A row = lane's bin; bins >48 get zero weights) ----
    int bin = (wid >> 1) * 32 + lane31;      // 0..63
    int ph = bin / 7;                        // up to 9 for dummy bins
    int pw = bin - ph * 7;
    float wr0, wr1, wr2; int yl0;
    {
        float c0 = fmaf((float)ph, bin_h, yq);
        float c1 = c0 + hbh;
        float v0 = (c0 >= -1.0f && c0 <= 50.0f) ? 1.0f : 0.0f;
        float v1 = (c1 >= -1.0f && c1 <= 50.0f) ? 1.0f : 0.0f;
        float cl0 = fminf(fmaxf(c0, 0.0f), 49.0f);
        float cl1 = fminf(fmaxf(c1, 0.0f), 49.0f);
        int l0 = min(max((int)floorf(cl0), 0), 48);
        int l1 = min(max((int)floorf(cl1), 0), 48);
        float f0 = cl0 - (float)l0, g0 = 1.0f - f0;
        float f1 = cl1 - (float)l1, g1 = 1.0f - f1;
        int dq = l1 - l0;                    // 0 or 1
        wr0 = v0 * g0 + ((dq == 0) ? v1 * g1 : 0.0f);
        wr1 = v0 * f0 + ((dq == 0) ? v1 * f1 : v1 * g1);
        wr2 = (dq == 0) ? 0.0f : v1 * f1;
        yl0 = l0;
    }
    float u0, u1, u2; int xl0;
    {
        float c0 = fmaf((float)pw, bin_w, xq);
        float c1 = c0 + hbw;
        float v0 = (c0 >= -1.0f && c0 <= 50.0f) ? 1.0f : 0.0f;
        float v1 = (c1 >= -1.0f && c1 <= 50.0f) ? 1.0f : 0.0f;
        float cl0 = fminf(fmaxf(c0, 0.0f), 49.0f);
        float cl1 = fminf(fmaxf(c1, 0.0f), 49.0f);
        int l0 = min(max((int)floorf(cl0), 0), 48);
        int l1 = min(max((int)floorf(cl1), 0), 48);
        float f0 = cl0 - (float)l0, g0 = 1.0f - f0;
        float f1 = cl1 - (float)l1, g1 = 1.0f - f1;
        int dq = l1 - l0;
        u0 = v0 * g0 + ((dq == 0) ? v1 * g1 : 0.0f);
        u1 = v0 * f0 + ((dq == 0) ? v1 * f1 : v1 * g1);
        u2 = (dq == 0) ? 0.0f : v1 * f1;
        xl0 = l0;
    }
    int ry0 = yl0 - rb;                      // 0..13
    int cc0 = xl0 - cb;                      // 0..13

    // ---- A rows in registers: cols hi*8+j of the 16-col window ----
    bf16x8 aw0, aw1, aw2;
    #pragma unroll
    for (int j = 0; j < 8; ++j) {
        int colj = hi * 8 + j;
        float uc = (colj == cc0) ? u0
                 : ((colj == cc0 + 1) ? u1 : ((colj == cc0 + 2) ? u2 : 0.0f));
        __hip_bfloat16 h0 = __float2bfloat16(wr0 * uc);
        __hip_bfloat16 h1 = __float2bfloat16(wr1 * uc);
        __hip_bfloat16 h2 = __float2bfloat16(wr2 * uc);
        aw0[j] = *(short*)&h0;
        aw1[j] = *(short*)&h1;
        aw2[j] = *(short*)&h2;
    }
    bf16x8 awz = {};

    // ---- MFMA main loop ----
    int ch0 = (wid & 1) * 32 + lane31;       // N-tile pair {ch0, ch0+64}
    int ch1 = ch0 + 64;
    int rot0 = ch0 >> 2, rot1 = ch1 >> 2;

    f32x16 acc0 = {}, acc1 = {};
    for (int chunk = 0; chunk < nch; ++chunk) {
        // repack current regs -> Vl (A regs dead afterwards)
        u4v lo0, hi0, lo1, hi1;
        lo0[0] = (A0[0] & 0xffffu) | (A1[0] << 16);
        lo0[1] = (A2[0] & 0xffffu) | (A3[0] << 16);
        lo0[2] = (A4[0] & 0xffffu) | (A5[0] << 16);
        lo0[3] = (A6[0] & 0xffffu) | (A7[0] << 16);
        hi0[0] = (A0[0] >> 16) | (A1[0] & 0xffff0000u);
        hi0[1] = (A2[0] >> 16) | (A3[0] & 0xffff0000u);
        hi0[2] = (A4[0] >> 16) | (A5[0] & 0xffff0000u);
        hi0[3] = (A6[0] >> 16) | (A7[0] & 0xffff0000u);
        lo1[0] = (A0[1] & 0xffffu) | (A1[1] << 16);
        lo1[1] = (A2[1] & 0xffffu) | (A3[1] << 16);
        lo1[2] = (A4[1] & 0xffffu) | (A5[1] << 16);
        lo1[3] = (A6[1] & 0xffffu) | (A7[1] << 16);
        hi1[0] = (A0[1] >> 16) | (A1[1] & 0xffff0000u);
        hi1[1] = (A2[1] >> 16) | (A3[1] & 0xffff0000u);
        hi1[2] = (A4[1] >> 16) | (A5[1] & 0xffff0000u);
        hi1[3] = (A6[1] >> 16) | (A7[1] & 0xffff0000u);
        *(u4v*)&Vl[(chA    ) * 64 + rotw * 8] = lo0;
        *(u4v*)&Vl[(chA + 1) * 64 + rotw * 8] = hi0;
        *(u4v*)&Vl[(chA + 2) * 64 + rotw * 8] = lo1;
        *(u4v*)&Vl[(chA + 3) * 64 + rotw * 8] = hi1;
        __syncthreads();                     // Vl ready

        if (chunk + 1 < nch) {               // next chunk's loads reuse A regs;
            int r0 = rb + (chunk + 1) * 4 + tg;   // latency hides under MFMA
            const unsigned int* rp = slabU + (r0 * WW + cb + half * 8) * 64 + 2 * cq;
            A0 = *(const u2v*)(rp);       A1 = *(const u2v*)(rp + 64);
            A2 = *(const u2v*)(rp + 128); A3 = *(const u2v*)(rp + 192);
            A4 = *(const u2v*)(rp + 256); A5 = *(const u2v*)(rp + 320);
            A6 = *(const u2v*)(rp + 384); A7 = *(const u2v*)(rp + 448);
        }

        #pragma unroll
        for (int kl = 0; kl < 4; ++kl) {
            int kk = chunk * 4 + kl;
            int rel = kk - ry0;
            bf16x8 av = (rel == 0) ? aw0
                      : ((rel == 1) ? aw1 : ((rel == 2) ? aw2 : awz));
            bf16x8 bv0 = *(const bf16x8*)&Vl[ch0 * 64 + (((kl * 2 + hi) + rot0) & 7) * 8];
            bf16x8 bv1 = *(const bf16x8*)&Vl[ch1 * 64 + (((kl * 2 + hi) + rot1) & 7) * 8];
            acc0 = __builtin_amdgcn_mfma_f32_32x32x16_bf16(av, bv0, acc0, 0, 0, 0);
            acc1 = __builtin_amdgcn_mfma_f32_32x32x16_bf16(av, bv1, acc1, 0, 0, 0);
        }
        __syncthreads();                     // reads done before next ds_write
    }

    // ---- epilogue (R14 verbatim): 2 passes of 64 ch through Vl-as-solh ----
    int m = wid >> 1;
    int obase = (n * C_TOTAL + g * CG) * NPOS;

    #pragma unroll
    for (int q = 0; q < 4; ++q) {            // pass 0: acc0, ch 0..63
        int bin0 = m * 32 + 8 * q + 4 * hi;  // C/D row = (reg&3)+8*(reg>>2)+4*hi
        if (bin0 <= 48) {
            f4a v;
            v[0] = acc0[4*q]; v[1] = acc0[4*q+1];
            v[2] = acc0[4*q+2]; v[3] = acc0[4*q+3];
            *(f4a*)&solh[ch0 * 52 + bin0] = v;
        }
    }
    __syncthreads();
    #pragma unroll
    for (int k2 = 0; k2 < 4; ++k2) {
        int t = k2 * 256 + tid;
        if (t < 784) {                       // 64*49/4
            f4a o;
            #pragma unroll
            for (int i2 = 0; i2 < 4; ++i2) {
                int f = 4 * t + i2;
                int fch = f / 49;
                int fbin = f - fch * 49;
                o[i2] = solh[fch * 52 + fbin] * 0.25f;
            }
            *(f4a*)(out + obase + 4 * t) = o;
        }
    }
    __syncthreads();
    #pragma unroll
    for (int q = 0; q < 4; ++q) {            // pass 1: acc1, ch 64..127
        int bin0 = m * 32 + 8 * q + 4 * hi;
        if (bin0 <= 48) {
            f4a v;
            v[0] = acc1[4*q]; v[1] = acc1[4*q+1];
            v[2] = acc1[4*q+2]; v[3] = acc1[4*q+3];
            *(f4a*)&solh[ch0 * 52 + bin0] = v;   // local ch = ch1-64 = ch0
        }
    }
    __syncthreads();
    #pragma unroll
    for (int k2 = 0; k2 < 4; ++k2) {
        int t = k2 * 256 + tid;
        if (t < 784) {
            f4a o;
            #pragma unroll
            for (int i2 = 0; i2 < 4; ++i2) {
                int f = 4 * t + i2;
                int fch = f / 49;
                int fbin = f - fch * 49;
                o[i2] = solh[fch * 52 + fbin] * 0.25f;
            }
            *(f4a*)(out + obase + 64 * NPOS + 4 * t) = o;
        }
    }
}

// ---- Fallback (fp32 direct, ~R7) if workspace too small --------------------
__global__ __launch_bounds__(256) void roi_align_fallback(
    const float* __restrict__ data, const float* __restrict__ rois,
    float* __restrict__ out, int H, int W, int N)
{
    __shared__ __align__(16) float so[64 * NPOS];
    int i   = blockIdx.x;
    int xcd = i & (NXCD - 1);
    int j   = i >> 3;
    int scl = (j >= N) ? 1 : 0;
    int n   = j - scl * N;
    int superchunk = xcd * 2 + scl;
    int t = threadIdx.x;
    bool active = (t < 5 * NPOS);
    int tt = active ? t : 0;
    int s  = tt % NPOS;
    int g  = tt / NPOS;
    int cbase = g * 13;
    int cnt = (g < 4) ? 13 : 12;
    int pw = s % PW;
    int ph = s / PW;
    if (active) {
        const float* roi = rois + n * 5;
        int   b  = (int)roi[0];
        float x1 = roi[1] * SPATIAL_SCALE, y1 = roi[2] * SPATIAL_SCALE;
        float x2 = roi[3] * SPATIAL_SCALE, y2 = roi[4] * SPATIAL_SCALE;
        float roi_w = fmaxf(x2 - x1, 1.0f), roi_h = fmaxf(y2 - y1, 1.0f);
        float bin_w = roi_w * (1.0f / PW), bin_h = roi_h * (1.0f / PH);
        float xc0 = x1 + ((float)(pw * 2 + 0) + 0.5f) * bin_w * 0.5f;
        float xc1 = x1 + ((float)(pw * 2 + 1) + 0.5f) * bin_w * 0.5f;
        float vx0 = (xc0 >= -1.0f && xc0 <= (float)W) ? 1.0f : 0.0f;
        float vx1 = (xc1 >= -1.0f && xc1 <= (float)W) ? 1.0f : 0.0f;
        float xcl0 = fminf(fmaxf(xc0, 0.0f), (float)(W - 1));
        float xcl1 = fminf(fmaxf(xc1, 0.0f), (float)(W - 1));
        int xl0 = min(max((int)floorf(xcl0), 0), W - 2);
        int xl1 = min(max((int)floorf(xcl1), 0), W - 2);
        float lx0 = xcl0 - (float)xl0, hx0 = 1.0f - lx0;
        float lx1 = xcl1 - (float)xl1, hx1 = 1.0f - lx1;
        int xb = min(xl0 & ~1, W - 4);
        int p0 = xl0 - xb, p1 = xl1 - xb;
        float w4[4];
        #pragma unroll
        for (int k = 0; k < 4; ++k) {
            float a = (p0 == k) ? hx0 : ((p0 + 1 == k) ? lx0 : 0.0f);
            float c = (p1 == k) ? hx1 : ((p1 + 1 == k) ? lx1 : 0.0f);
            w4[k] = vx0 * a + vx1 * c;
        }
        float yc0 = y1 + ((float)(ph * 2 + 0) + 0.5f) * bin_h * 0.5f;
        float yc1 = y1 + ((float)(ph * 2 + 1) + 0.5f) * bin_h * 0.5f;
        float vy0 = (yc0 >= -1.0f && yc0 <= (float)H) ? 1.0f : 0.0f;
        float vy1 = (yc1 >= -1.0f && yc1 <= (float)H) ? 1.0f : 0.0f;
        float ycl0 = fminf(fmaxf(yc0, 0.0f), (float)(H - 1));
        float ycl1 = fminf(fmaxf(yc1, 0.0f), (float)(H - 1));
        int yl0 = min(max((int)floorf(ycl0), 0), H - 2);
        int yl1 = min(max((int)floorf(ycl1), 0), H - 2);
        float ly0 = ycl0 - (float)yl0, hy0 = 1.0f - ly0;
        float ly1 = ycl1 - (float)yl1, hy1 = 1.0f - ly1;
        float wy0 = 0.25f * vy0 * hy0, wy1 = 0.25f * vy0 * ly0;
        float wy2 = 0.25f * vy1 * hy1, wy3 = 0.25f * vy1 * ly1;
        int q = yl1 - yl0;
        float wr0 = wy0 + ((q == 0) ? wy2 : 0.0f);
        float wr1 = wy1 + ((q == 0) ? wy3 : wy2);
        float wr2 = (q == 0) ? 0.0f : wy3;
        int row0 = yl0;
        int row2 = min(yl0 + 2, H - 1);
        float wv[3][4];
        #pragma unroll
        for (int k = 0; k < 4; ++k) {
            wv[0][k] = wr0 * w4[k]; wv[1][k] = wr1 * w4[k]; wv[2][k] = wr2 * w4[k];
        }
        int c0 = superchunk * 64 + cbase;
        const int HW = H * W;
        unsigned slab = (unsigned)(b * C_TOTAL + c0) * (unsigned)HW;
        unsigned o0 = slab + (unsigned)(row0 * W + xb);
        unsigned o1 = o0 + (unsigned)W;
        unsigned o2 = slab + (unsigned)(row2 * W + xb);
        int ldsbase = cbase * NPOS + s;
        f4v a0 = *(const f4v*)(data + o0);
        f4v a1 = *(const f4v*)(data + o1);
        f4v a2 = *(const f4v*)(data + o2);
        int jj = 0;
        for (; jj < cnt - 1; ++jj) {
            o0 += HW; o1 += HW; o2 += HW;
            f4v b0 = *(const f4v*)(data + o0);
            f4v b1 = *(const f4v*)(data + o1);
            f4v b2 = *(const f4v*)(data + o2);
            float acc = wv[0][0]*a0.x + wv[0][1]*a0.y + wv[0][2]*a0.z + wv[0][3]*a0.w
                      + wv[1][0]*a1.x + wv[1][1]*a1.y + wv[1][2]*a1.z + wv[1][3]*a1.w
                      + wv[2][0]*a2.x + wv[2][1]*a2.y + wv[2][2]*a2.z + wv[2][3]*a2.w;
            so[ldsbase + jj * NPOS] = acc;
            a0 = b0; a1 = b1; a2 = b2;
        }
        float acc = wv[0][0]*a0.x + wv[0][1]*a0.y + wv[0][2]*a0.z + wv[0][3]*a0.w
                  + wv[1][0]*a1.x + wv[1][1]*a1.y + wv[1][2]*a1.z + wv[1][3]*a1.w
                  + wv[2][0]*a2.x + wv[2][1]*a2.y + wv[2][2]*a2.z + wv[2][3]*a2.w;
        so[ldsbase + jj * NPOS] = acc;
    }
    __syncthreads();
    unsigned base = (unsigned)(n * C_TOTAL + superchunk * 64) * NPOS;
    f4a* dst = (f4a*)(out + base);
    const f4a* src = (const f4a*)so;
    int tid = threadIdx.x;
    dst[tid] = src[tid];
    dst[256 + tid] = src[256 + tid];
    dst[512 + tid] = src[512 + tid];
    if (tid < 16) dst[768 + tid] = src[768 + tid];
}

extern "C" void kernel_launch(void* const* d_in, const int* in_sizes, int n_in,
                              void* d_out, int out_size, void* d_ws, size_t ws_size,
                              hipStream_t stream) {
    const float* data = (const float*)d_in[0];
    const float* rois = (const float*)d_in[1];
    float* out = (float*)d_out;
    const int N = in_sizes[1] / 5;

    if (ws_size >= TB_BYTES) {
        __hip_bfloat16* Tb = (__hip_bfloat16*)d_ws;
        transpose_bf16_kernel<<<2 * HH * NXCD, 256, 0, stream>>>(data, Tb);
        roi_mfma_kernel<<<N * NXCD, 256, 0, stream>>>(
            (const unsigned int*)d_ws, rois, out, N);
    } else {
        roi_align_fallback<<<N * 16, 256, 0, stream>>>(data, rois, out, HH, WW, N);
    }
}

// Round 19
// 43.484 us; speedup vs baseline: 1.1185x; 1.0044x over previous
//
#include <hip/hip_runtime.h>
#include <hip/hip_bf16.h>

#define SPATIAL_SCALE 0.0625f
#define PH 7
#define PW 7
#define C_TOTAL 1024
#define NXCD 8
#define NPOS 49
#define CG 128
#define HH 50
#define WW 50
#define TB_BYTES (2ULL * NXCD * HH * WW * CG * 2ULL)   // 10,240,000 B (bf16)

typedef short bf16x8 __attribute__((ext_vector_type(8)));
typedef float f32x16 __attribute__((ext_vector_type(16)));
typedef float f4a __attribute__((ext_vector_type(4), aligned(16)));
typedef float f4v __attribute__((ext_vector_type(4), aligned(8)));
typedef unsigned int u4v __attribute__((ext_vector_type(4), aligned(16)));
typedef unsigned int u2v __attribute__((ext_vector_type(2), aligned(8)));

// ---- Kernel 1: NCHW fp32 -> [b][g][y][x][c128] bf16 channels-last ----------
__global__ __launch_bounds__(256) void transpose_bf16_kernel(
    const float* __restrict__ in, __hip_bfloat16* __restrict__ Tb)
{
    __shared__ float lds[CG][WW + 1];
    int bid = blockIdx.x;            // (b*50 + y)*8 + g
    int g = bid & 7;
    int r = bid >> 3;
    int y = r % HH;
    int b = r / HH;
    int tid = threadIdx.x;

    const float* src = in + (size_t)(b * C_TOTAL + g * CG) * (HH * WW) + y * WW;
    #pragma unroll
    for (int it = 0; it < 25; ++it) {        // 6400 = 128c x 50x
        int idx = it * 256 + tid;
        int c = idx / WW;
        int x = idx - c * WW;
        lds[c][x] = src[c * (HH * WW) + x];
    }
    __syncthreads();
    __hip_bfloat16* dst = Tb + (size_t)((b * NXCD + g) * (HH * WW) + y * WW) * CG;
    #pragma unroll
    for (int it = 0; it < 25; ++it) {
        int idx = it * 256 + tid;
        int x = idx >> 7;                    // 0..49
        int c = idx & 127;
        dst[x * CG + c] = __float2bfloat16(lds[c][x]);
    }
}

// ---- Kernel 2: MFMA ROI align (R14 + double-buffered Vl, 1 barrier/chunk) --
// Block = (roi n, slab g): 128 ch, 4 waves. blockIdx&7=g -> XCD pin.
// Wave (m=wid>>1, nt=wid&1): A = bin m*32+lane31 (3 bf16x8 regs), B = ch
// {nt*32, +64} (2 ds_reads/kl), 2 accumulators. Ping-pong: stage c+1 into
// buf[(c+1)&1] AFTER mfma(c) from buf[c&1]; single barrier per chunk.
// WAR safety: each wave's c-reads drain (lgkmcnt) before it passes barrier
// c+1, so buf reuse at c+2 is race-free. Epilogue: R14's 2-pass solh staging.
__global__ __launch_bounds__(256) void roi_mfma_kernel(
    const unsigned int* __restrict__ Tw,   // channels-last bf16 viewed as u32
    const float* __restrict__ rois,
    float* __restrict__ out, int N)
{
    __shared__ __align__(16) short Vl[2 * CG * 64];  // 32768 B (2 buffers)
    float* solh = (float*)Vl;                        // [64][52] f32 reuse

    int g   = blockIdx.x & (NXCD - 1);
    int n   = blockIdx.x >> 3;
    int tid = threadIdx.x;
    int wid = tid >> 6, lane = tid & 63, lane31 = lane & 31, hi = lane >> 5;

    const float* roi = rois + n * 5;
    int   b  = (int)roi[0];
    float x1 = roi[1] * SPATIAL_SCALE;
    float y1 = roi[2] * SPATIAL_SCALE;
    float x2 = roi[3] * SPATIAL_SCALE;
    float y2 = roi[4] * SPATIAL_SCALE;
    float bin_w = fmaxf(x2 - x1, 1.0f) * (1.0f / 7.0f);
    float bin_h = fmaxf(y2 - y1, 1.0f) * (1.0f / 7.0f);
    float hbw = 0.5f * bin_w, hbh = 0.5f * bin_h;
    float xq = x1 + 0.5f * hbw;              // xc0(pw) = pw*bin_w + xq
    float yq = y1 + 0.5f * hbh;

    // ---- uniform window base ----
    int minr = 48, maxr0 = 0, minc = 48;
    #pragma unroll
    for (int i = 0; i < 7; ++i) {
        float yc = fmaf((float)i, bin_h, yq);
        int yl = min(max((int)floorf(fminf(fmaxf(yc, 0.0f), 49.0f)), 0), 48);
        minr = min(minr, yl); maxr0 = max(maxr0, yl);
        float xc = fmaf((float)i, bin_w, xq);
        int xl = min(max((int)floorf(fminf(fmaxf(xc, 0.0f), 49.0f)), 0), 48);
        minc = min(minc, xl);
    }
    int rb = min(minr, 34);
    int cb = min(minc, 34) & ~1;             // even -> 4B-aligned staging
    int nch = ((min(maxr0 + 2, 49) - rb) >> 2) + 1;   // 1..4 chunks

    // ---- chunk-0 loads issued NOW (latency hides under preamble below) ----
    int cq   = tid & 31;
    int half = (tid >> 5) & 1;
    int tg   = tid >> 6;
    int chA  = 4 * cq;
    int rotw = ((tg * 2 + half) + cq) & 7;
    const unsigned int* slabU = Tw + (size_t)(b * NXCD + g) * (HH * WW * 64);

    u2v A0, A1, A2, A3, A4, A5, A6, A7;
    {
        int r0 = rb + tg;
        const unsigned int* rp = slabU + (r0 * WW + cb + half * 8) * 64 + 2 * cq;
        A0 = *(const u2v*)(rp);       A1 = *(const u2v*)(rp + 64);
        A2 = *(const u2v*)(rp + 128); A3 = *(const u2v*)(rp + 192);
        A4 = *(const u2v*)(rp + 256); A5 = *(const u2v*)(rp + 320);
        A6 = *(const u2v*)(rp + 384); A7 = *(const u2v*)(rp + 448);
    }

    // ---- own-bin params (A row = lane's bin; bins >48 get zero weights) ----
    int bin = (wid >> 1) * 32 + lane31;      // 0..63
    int ph = bin / 7;                        // up to 9 for dummy bins
    int pw = bin - ph * 7;
    float wr0, wr1, wr2; int yl0;
    {
        float c0 = fmaf((float)ph, bin_h, yq);
        float c1 = c0 + hbh;
        float v0 = (c0 >= -1.0f && c0 <= 50.0f) ? 1.0f : 0.0f;
        float v1 = (c1 >= -1.0f && c1 <= 50.0f) ? 1.0f : 0.0f;
        float cl0 = fminf(fmaxf(c0, 0.0f), 49.0f);
        float cl1 = fminf(fmaxf(c1, 0.0f), 49.0f);
        int l0 = min(max((int)floorf(cl0), 0), 48);
        int l1 = min(max((int)floorf(cl1), 0), 48);
        float f0 = cl0 - (float)l0, g0 = 1.0f - f0;
        float f1 = cl1 - (float)l1, g1 = 1.0f - f1;
        int dq = l1 - l0;                    // 0 or 1
        wr0 = v0 * g0 + ((dq == 0) ? v1 * g1 : 0.0f);
        wr1 = v0 * f0 + ((dq == 0) ? v1 * f1 : v1 * g1);
        wr2 = (dq == 0) ? 0.0f : v1 * f1;
        yl0 = l0;
    }
    float u0, u1, u2; int xl0;
    {
        float c0 = fmaf((float)pw, bin_w, xq);
        float c1 = c0 + hbw;
        float v0 = (c0 >= -1.0f && c0 <= 50.0f) ? 1.0f : 0.0f;
        float v1 = (c1 >= -1.0f && c1 <= 50.0f) ? 1.0f : 0.0f;
        float cl0 = fminf(fmaxf(c0, 0.0f), 49.0f);
        float cl1 = fminf(fmaxf(c1, 0.0f), 49.0f);
        int l0 = min(max((int)floorf(cl0), 0), 48);
        int l1 = min(max((int)floorf(cl1), 0), 48);
        float f0 = cl0 - (float)l0, g0 = 1.0f - f0;
        float f1 = cl1 - (float)l1, g1 = 1.0f - f1;
        int dq = l1 - l0;
        u0 = v0 * g0 + ((dq == 0) ? v1 * g1 : 0.0f);
        u1 = v0 * f0 + ((dq == 0) ? v1 * f1 : v1 * g1);
        u2 = (dq == 0) ? 0.0f : v1 * f1;
        xl0 = l0;
    }
    int ry0 = yl0 - rb;                      // 0..13
    int cc0 = xl0 - cb;                      // 0..13

    // ---- A rows in registers: cols hi*8+j of the 16-col window ----
    bf16x8 aw0, aw1, aw2;
    #pragma unroll
    for (int j = 0; j < 8; ++j) {
        int colj = hi * 8 + j;
        float uc = (colj == cc0) ? u0
                 : ((colj == cc0 + 1) ? u1 : ((colj == cc0 + 2) ? u2 : 0.0f));
        __hip_bfloat16 h0 = __float2bfloat16(wr0 * uc);
        __hip_bfloat16 h1 = __float2bfloat16(wr1 * uc);
        __hip_bfloat16 h2 = __float2bfloat16(wr2 * uc);
        aw0[j] = *(short*)&h0;
        aw1[j] = *(short*)&h1;
        aw2[j] = *(short*)&h2;
    }
    bf16x8 awz = {};

    // ---- staging helper: repack A regs -> given buffer ----
    auto stage = [&](short* buf) {
        u4v lo0, hi0, lo1, hi1;
        lo0[0] = (A0[0] & 0xffffu) | (A1[0] << 16);
        lo0[1] = (A2[0] & 0xffffu) | (A3[0] << 16);
        lo0[2] = (A4[0] & 0xffffu) | (A5[0] << 16);
        lo0[3] = (A6[0] & 0xffffu) | (A7[0] << 16);
        hi0[0] = (A0[0] >> 16) | (A1[0] & 0xffff0000u);
        hi0[1] = (A2[0] >> 16) | (A3[0] & 0xffff0000u);
        hi0[2] = (A4[0] >> 16) | (A5[0] & 0xffff0000u);
        hi0[3] = (A6[0] >> 16) | (A7[0] & 0xffff0000u);
        lo1[0] = (A0[1] & 0xffffu) | (A1[1] << 16);
        lo1[1] = (A2[1] & 0xffffu) | (A3[1] << 16);
        lo1[2] = (A4[1] & 0xffffu) | (A5[1] << 16);
        lo1[3] = (A6[1] & 0xffffu) | (A7[1] << 16);
        hi1[0] = (A0[1] >> 16) | (A1[1] & 0xffff0000u);
        hi1[1] = (A2[1] >> 16) | (A3[1] & 0xffff0000u);
        hi1[2] = (A4[1] >> 16) | (A5[1] & 0xffff0000u);
        hi1[3] = (A6[1] >> 16) | (A7[1] & 0xffff0000u);
        *(u4v*)&buf[(chA    ) * 64 + rotw * 8] = lo0;
        *(u4v*)&buf[(chA + 1) * 64 + rotw * 8] = hi0;
        *(u4v*)&buf[(chA + 2) * 64 + rotw * 8] = lo1;
        *(u4v*)&buf[(chA + 3) * 64 + rotw * 8] = hi1;
    };

    // ---- MFMA main loop: ping-pong, one barrier per chunk ----
    int ch0 = (wid & 1) * 32 + lane31;       // N-tile pair {ch0, ch0+64}
    int ch1 = ch0 + 64;
    int rot0 = ch0 >> 2, rot1 = ch1 >> 2;

    stage(Vl);                               // chunk 0 -> buf0
    __syncthreads();                         // buf0 ready

    f32x16 acc0 = {}, acc1 = {};
    for (int chunk = 0; chunk < nch; ++chunk) {
        short* cur = Vl + (chunk & 1) * (CG * 64);

        if (chunk + 1 < nch) {               // T14: issue next chunk's loads
            int r0 = rb + (chunk + 1) * 4 + tg;
            const unsigned int* rp = slabU + (r0 * WW + cb + half * 8) * 64 + 2 * cq;
            A0 = *(const u2v*)(rp);       A1 = *(const u2v*)(rp + 64);
            A2 = *(const u2v*)(rp + 128); A3 = *(const u2v*)(rp + 192);
            A4 = *(const u2v*)(rp + 256); A5 = *(const u2v*)(rp + 320);
            A6 = *(const u2v*)(rp + 384); A7 = *(const u2v*)(rp + 448);
        }

        #pragma unroll
        for (int kl = 0; kl < 4; ++kl) {
            int kk = chunk * 4 + kl;
            int rel = kk - ry0;
            bf16x8 av = (rel == 0) ? aw0
                      : ((rel == 1) ? aw1 : ((rel == 2) ? aw2 : awz));
            bf16x8 bv0 = *(const bf16x8*)&cur[ch0 * 64 + (((kl * 2 + hi) + rot0) & 7) * 8];
            bf16x8 bv1 = *(const bf16x8*)&cur[ch1 * 64 + (((kl * 2 + hi) + rot1) & 7) * 8];
            acc0 = __builtin_amdgcn_mfma_f32_32x32x16_bf16(av, bv0, acc0, 0, 0, 0);
            acc1 = __builtin_amdgcn_mfma_f32_32x32x16_bf16(av, bv1, acc1, 0, 0, 0);
        }

        if (chunk + 1 < nch) {
            stage(Vl + ((chunk + 1) & 1) * (CG * 64));
            __syncthreads();                 // next buf ready; prior reads drained
        }
    }
    __syncthreads();                         // protect solh (=buf0) from reads

    // ---- epilogue (R14 verbatim): 2 passes of 64 ch through Vl-as-solh ----
    int m = wid >> 1;
    int obase = (n * C_TOTAL + g * CG) * NPOS;

    #pragma unroll
    for (int q = 0; q < 4; ++q) {            // pass 0: acc0, ch 0..63
        int bin0 = m * 32 + 8 * q + 4 * hi;  // C/D row = (reg&3)+8*(reg>>2)+4*hi
        if (bin0 <= 48) {
            f4a v;
            v[0] = acc0[4*q]; v[1] = acc0[4*q+1];
            v[2] = acc0[4*q+2]; v[3] = acc0[4*q+3];
            *(f4a*)&solh[ch0 * 52 + bin0] = v;
        }
    }
    __syncthreads();
    #pragma unroll
    for (int k2 = 0; k2 < 4; ++k2) {
        int t = k2 * 256 + tid;
        if (t < 784) {                       // 64*49/4
            f4a o;
            #pragma unroll
            for (int i2 = 0; i2 < 4; ++i2) {
                int f = 4 * t + i2;
                int fch = f / 49;
                int fbin = f - fch * 49;
                o[i2] = solh[fch * 52 + fbin] * 0.25f;
            }
            *(f4a*)(out + obase + 4 * t) = o;
        }
    }
    __syncthreads();
    #pragma unroll
    for (int q = 0; q < 4; ++q) {            // pass 1: acc1, ch 64..127
        int bin0 = m * 32 + 8 * q + 4 * hi;
        if (bin0 <= 48) {
            f4a v;
            v[0] = acc1[4*q]; v[1] = acc1[4*q+1];
            v[2] = acc1[4*q+2]; v[3] = acc1[4*q+3];
            *(f4a*)&solh[ch0 * 52 + bin0] = v;   // local ch = ch1-64 = ch0
        }
    }
    __syncthreads();
    #pragma unroll
    for (int k2 = 0; k2 < 4; ++k2) {
        int t = k2 * 256 + tid;
        if (t < 784) {
            f4a o;
            #pragma unroll
            for (int i2 = 0; i2 < 4; ++i2) {
                int f = 4 * t + i2;
                int fch = f / 49;
                int fbin = f - fch * 49;
                o[i2] = solh[fch * 52 + fbin] * 0.25f;
            }
            *(f4a*)(out + obase + 64 * NPOS + 4 * t) = o;
        }
    }
}

// ---- Fallback (fp32 direct, ~R7) if workspace too small --------------------
__global__ __launch_bounds__(256) void roi_align_fallback(
    const float* __restrict__ data, const float* __restrict__ rois,
    float* __restrict__ out, int H, int W, int N)
{
    __shared__ __align__(16) float so[64 * NPOS];
    int i   = blockIdx.x;
    int xcd = i & (NXCD - 1);
    int j   = i >> 3;
    int scl = (j >= N) ? 1 : 0;
    int n   = j - scl * N;
    int superchunk = xcd * 2 + scl;
    int t = threadIdx.x;
    bool active = (t < 5 * NPOS);
    int tt = active ? t : 0;
    int s  = tt % NPOS;
    int g  = tt / NPOS;
    int cbase = g * 13;
    int cnt = (g < 4) ? 13 : 12;
    int pw = s % PW;
    int ph = s / PW;
    if (active) {
        const float* roi = rois + n * 5;
        int   b  = (int)roi[0];
        float x1 = roi[1] * SPATIAL_SCALE, y1 = roi[2] * SPATIAL_SCALE;
        float x2 = roi[3] * SPATIAL_SCALE, y2 = roi[4] * SPATIAL_SCALE;
        float roi_w = fmaxf(x2 - x1, 1.0f), roi_h = fmaxf(y2 - y1, 1.0f);
        float bin_w = roi_w * (1.0f / PW), bin_h = roi_h * (1.0f / PH);
        float xc0 = x1 + ((float)(pw * 2 + 0) + 0.5f) * bin_w * 0.5f;
        float xc1 = x1 + ((float)(pw * 2 + 1) + 0.5f) * bin_w * 0.5f;
        float vx0 = (xc0 >= -1.0f && xc0 <= (float)W) ? 1.0f : 0.0f;
        float vx1 = (xc1 >= -1.0f && xc1 <= (float)W) ? 1.0f : 0.0f;
        float xcl0 = fminf(fmaxf(xc0, 0.0f), (float)(W - 1));
        float xcl1 = fminf(fmaxf(xc1, 0.0f), (float)(W - 1));
        int xl0 = min(max((int)floorf(xcl0), 0), W - 2);
        int xl1 = min(max((int)floorf(xcl1), 0), W - 2);
        float lx0 = xcl0 - (float)xl0, hx0 = 1.0f - lx0;
        float lx1 = xcl1 - (float)xl1, hx1 = 1.0f - lx1;
        int xb = min(xl0 & ~1, W - 4);
        int p0 = xl0 - xb, p1 = xl1 - xb;
        float w4[4];
        #pragma unroll
        for (int k = 0; k < 4; ++k) {
            float a = (p0 == k) ? hx0 : ((p0 + 1 == k) ? lx0 : 0.0f);
            float c = (p1 == k) ? hx1 : ((p1 + 1 == k) ? lx1 : 0.0f);
            w4[k] = vx0 * a + vx1 * c;
        }
        float yc0 = y1 + ((float)(ph * 2 + 0) + 0.5f) * bin_h * 0.5f;
        float yc1 = y1 + ((float)(ph * 2 + 1) + 0.5f) * bin_h * 0.5f;
        float vy0 = (yc0 >= -1.0f && yc0 <= (float)H) ? 1.0f : 0.0f;
        float vy1 = (yc1 >= -1.0f && yc1 <= (float)H) ? 1.0f : 0.0f;
        float ycl0 = fminf(fmaxf(yc0, 0.0f), (float)(H - 1));
        float ycl1 = fminf(fmaxf(yc1, 0.0f), (float)(H - 1));
        int yl0 = min(max((int)floorf(ycl0), 0), H - 2);
        int yl1 = min(max((int)floorf(ycl1), 0), H - 2);
        float ly0 = ycl0 - (float)yl0, hy0 = 1.0f - ly0;
        float ly1 = ycl1 - (float)yl1, hy1 = 1.0f - ly1;
        float wy0 = 0.25f * vy0 * hy0, wy1 = 0.25f * vy0 * ly0;
        float wy2 = 0.25f * vy1 * hy1, wy3 = 0.25f * vy1 * ly1;
        int q = yl1 - yl0;
        float wr0 = wy0 + ((q == 0) ? wy2 : 0.0f);
        float wr1 = wy1 + ((q == 0) ? wy3 : wy2);
        float wr2 = (q == 0) ? 0.0f : wy3;
        int row0 = yl0;
        int row2 = min(yl0 + 2, H - 1);
        float wv[3][4];
        #pragma unroll
        for (int k = 0; k < 4; ++k) {
            wv[0][k] = wr0 * w4[k]; wv[1][k] = wr1 * w4[k]; wv[2][k] = wr2 * w4[k];
        }
        int c0 = superchunk * 64 + cbase;
        const int HW = H * W;
        unsigned slab = (unsigned)(b * C_TOTAL + c0) * (unsigned)HW;
        unsigned o0 = slab + (unsigned)(row0 * W + xb);
        unsigned o1 = o0 + (unsigned)W;
        unsigned o2 = slab + (unsigned)(row2 * W + xb);
        int ldsbase = cbase * NPOS + s;
        f4v a0 = *(const f4v*)(data + o0);
        f4v a1 = *(const f4v*)(data + o1);
        f4v a2 = *(const f4v*)(data + o2);
        int jj = 0;
        for (; jj < cnt - 1; ++jj) {
            o0 += HW; o1 += HW; o2 += HW;
            f4v b0 = *(const f4v*)(data + o0);
            f4v b1 = *(const f4v*)(data + o1);
            f4v b2 = *(const f4v*)(data + o2);
            float acc = wv[0][0]*a0.x + wv[0][1]*a0.y + wv[0][2]*a0.z + wv[0][3]*a0.w
                      + wv[1][0]*a1.x + wv[1][1]*a1.y + wv[1][2]*a1.z + wv[1][3]*a1.w
                      + wv[2][0]*a2.x + wv[2][1]*a2.y + wv[2][2]*a2.z + wv[2][3]*a2.w;
            so[ldsbase + jj * NPOS] = acc;
            a0 = b0; a1 = b1; a2 = b2;
        }
        float acc = wv[0][0]*a0.x + wv[0][1]*a0.y + wv[0][2]*a0.z + wv[0][3]*a0.w
                  + wv[1][0]*a1.x + wv[1][1]*a1.y + wv[1][2]*a1.z + wv[1][3]*a1.w
                  + wv[2][0]*a2.x + wv[2][1]*a2.y + wv[2][2]*a2.z + wv[2][3]*a2.w;
        so[ldsbase + jj * NPOS] = acc;
    }
    __syncthreads();
    unsigned base = (unsigned)(n * C_TOTAL + superchunk * 64) * NPOS;
    f4a* dst = (f4a*)(out + base);
    const f4a* src = (const f4a*)so;
    int tid = threadIdx.x;
    dst[tid] = src[tid];
    dst[256 + tid] = src[256 + tid];
    dst[512 + tid] = src[512 + tid];
    if (tid < 16) dst[768 + tid] = src[768 + tid];
}

extern "C" void kernel_launch(void* const* d_in, const int* in_sizes, int n_in,
                              void* d_out, int out_size, void* d_ws, size_t ws_size,
                              hipStream_t stream) {
    const float* data = (const float*)d_in[0];
    const float* rois = (const float*)d_in[1];
    float* out = (float*)d_out;
    const int N = in_sizes[1] / 5;

    if (ws_size >= TB_BYTES) {
        __hip_bfloat16* Tb = (__hip_bfloat16*)d_ws;
        transpose_bf16_kernel<<<2 * HH * NXCD, 256, 0, stream>>>(data, Tb);
        roi_mfma_kernel<<<N * NXCD, 256, 0, stream>>>(
            (const unsigned int*)d_ws, rois, out, N);
    } else {
        roi_align_fallback<<<N * 16, 256, 0, stream>>>(data, rois, out, HH, WW, N);
    }
}

// Round 20
// 42.605 us; speedup vs baseline: 1.1415x; 1.0206x over previous
//
#include <hip/hip_runtime.h>
#include <hip/hip_bf16.h>

#define SPATIAL_SCALE 0.0625f
#define PH 7
#define PW 7
#define C_TOTAL 1024
#define NXCD 8
#define NPOS 49
#define CG 128
#define HH 50
#define WW 50
#define TB_BYTES (2ULL * NXCD * HH * WW * CG * 2ULL)   // 10,240,000 B (bf16)

typedef short bf16x8 __attribute__((ext_vector_type(8)));
typedef float f32x16 __attribute__((ext_vector_type(16)));
typedef float f4a __attribute__((ext_vector_type(4), aligned(16)));
typedef float f4v __attribute__((ext_vector_type(4), aligned(8)));
typedef unsigned int u4v __attribute__((ext_vector_type(4), aligned(16)));
typedef unsigned int u2v __attribute__((ext_vector_type(2), aligned(8)));

// ---- Kernel 1: NCHW fp32 -> [b][g][y][x][c128] bf16 channels-last ----------
__global__ __launch_bounds__(256) void transpose_bf16_kernel(
    const float* __restrict__ in, __hip_bfloat16* __restrict__ Tb)
{
    __shared__ float lds[CG][WW + 1];
    int bid = blockIdx.x;            // (b*50 + y)*8 + g
    int g = bid & 7;
    int r = bid >> 3;
    int y = r % HH;
    int b = r / HH;
    int tid = threadIdx.x;

    const float* src = in + (size_t)(b * C_TOTAL + g * CG) * (HH * WW) + y * WW;
    #pragma unroll
    for (int it = 0; it < 25; ++it) {        // 6400 = 128c x 50x
        int idx = it * 256 + tid;
        int c = idx / WW;
        int x = idx - c * WW;
        lds[c][x] = src[c * (HH * WW) + x];
    }
    __syncthreads();
    __hip_bfloat16* dst = Tb + (size_t)((b * NXCD + g) * (HH * WW) + y * WW) * CG;
    #pragma unroll
    for (int it = 0; it < 25; ++it) {
        int idx = it * 256 + tid;
        int x = idx >> 7;                    // 0..49
        int c = idx & 127;
        dst[x * CG + c] = __float2bfloat16(lds[c][x]);
    }
}

// ---- Kernel 2: MFMA ROI align (R19 main loop + merged 1-pass epilogue) -----
// Block = (roi n, slab g): 128 ch, 4 waves. blockIdx&7=g -> XCD pin.
// Wave (m=wid>>1, nt=wid&1): A = bin m*32+lane31 (3 bf16x8 regs), B = ch
// {nt*32, +64} (2 ds_reads/kl), 2 accumulators. Ping-pong Vl[2], one barrier
// per chunk. Epilogue: single [128][52] f32 staging pass (fits the 32KB
// double-buffer), 2 barriers total, nontemporal coalesced b128 writeback
// (output stream bypasses L2 -> doesn't evict the pinned input slab).
__global__ __launch_bounds__(256) void roi_mfma_kernel(
    const unsigned int* __restrict__ Tw,   // channels-last bf16 viewed as u32
    const float* __restrict__ rois,
    float* __restrict__ out, int N)
{
    __shared__ __align__(16) short Vl[2 * CG * 64];  // 32768 B (2 buffers)
    float* solh = (float*)Vl;                        // [128][52] f32 = 26624 B

    int g   = blockIdx.x & (NXCD - 1);
    int n   = blockIdx.x >> 3;
    int tid = threadIdx.x;
    int wid = tid >> 6, lane = tid & 63, lane31 = lane & 31, hi = lane >> 5;

    const float* roi = rois + n * 5;
    int   b  = (int)roi[0];
    float x1 = roi[1] * SPATIAL_SCALE;
    float y1 = roi[2] * SPATIAL_SCALE;
    float x2 = roi[3] * SPATIAL_SCALE;
    float y2 = roi[4] * SPATIAL_SCALE;
    float bin_w = fmaxf(x2 - x1, 1.0f) * (1.0f / 7.0f);
    float bin_h = fmaxf(y2 - y1, 1.0f) * (1.0f / 7.0f);
    float hbw = 0.5f * bin_w, hbh = 0.5f * bin_h;
    float xq = x1 + 0.5f * hbw;              // xc0(pw) = pw*bin_w + xq
    float yq = y1 + 0.5f * hbh;

    // ---- uniform window base ----
    int minr = 48, maxr0 = 0, minc = 48;
    #pragma unroll
    for (int i = 0; i < 7; ++i) {
        float yc = fmaf((float)i, bin_h, yq);
        int yl = min(max((int)floorf(fminf(fmaxf(yc, 0.0f), 49.0f)), 0), 48);
        minr = min(minr, yl); maxr0 = max(maxr0, yl);
        float xc = fmaf((float)i, bin_w, xq);
        int xl = min(max((int)floorf(fminf(fmaxf(xc, 0.0f), 49.0f)), 0), 48);
        minc = min(minc, xl);
    }
    int rb = min(minr, 34);
    int cb = min(minc, 34) & ~1;             // even -> 4B-aligned staging
    int nch = ((min(maxr0 + 2, 49) - rb) >> 2) + 1;   // 1..4 chunks

    // ---- chunk-0 loads issued NOW (latency hides under preamble below) ----
    int cq   = tid & 31;
    int half = (tid >> 5) & 1;
    int tg   = tid >> 6;
    int chA  = 4 * cq;
    int rotw = ((tg * 2 + half) + cq) & 7;
    const unsigned int* slabU = Tw + (size_t)(b * NXCD + g) * (HH * WW * 64);

    u2v A0, A1, A2, A3, A4, A5, A6, A7;
    {
        int r0 = rb + tg;
        const unsigned int* rp = slabU + (r0 * WW + cb + half * 8) * 64 + 2 * cq;
        A0 = *(const u2v*)(rp);       A1 = *(const u2v*)(rp + 64);
        A2 = *(const u2v*)(rp + 128); A3 = *(const u2v*)(rp + 192);
        A4 = *(const u2v*)(rp + 256); A5 = *(const u2v*)(rp + 320);
        A6 = *(const u2v*)(rp + 384); A7 = *(const u2v*)(rp + 448);
    }

    // ---- own-bin params (A row = lane's bin; bins >48 get zero weights) ----
    int bin = (wid >> 1) * 32 + lane31;      // 0..63
    int ph = bin / 7;                        // up to 9 for dummy bins
    int pw = bin - ph * 7;
    float wr0, wr1, wr2; int yl0;
    {
        float c0 = fmaf((float)ph, bin_h, yq);
        float c1 = c0 + hbh;
        float v0 = (c0 >= -1.0f && c0 <= 50.0f) ? 1.0f : 0.0f;
        float v1 = (c1 >= -1.0f && c1 <= 50.0f) ? 1.0f : 0.0f;
        float cl0 = fminf(fmaxf(c0, 0.0f), 49.0f);
        float cl1 = fminf(fmaxf(c1, 0.0f), 49.0f);
        int l0 = min(max((int)floorf(cl0), 0), 48);
        int l1 = min(max((int)floorf(cl1), 0), 48);
        float f0 = cl0 - (float)l0, g0 = 1.0f - f0;
        float f1 = cl1 - (float)l1, g1 = 1.0f - f1;
        int dq = l1 - l0;                    // 0 or 1
        wr0 = v0 * g0 + ((dq == 0) ? v1 * g1 : 0.0f);
        wr1 = v0 * f0 + ((dq == 0) ? v1 * f1 : v1 * g1);
        wr2 = (dq == 0) ? 0.0f : v1 * f1;
        yl0 = l0;
    }
    float u0, u1, u2; int xl0;
    {
        float c0 = fmaf((float)pw, bin_w, xq);
        float c1 = c0 + hbw;
        float v0 = (c0 >= -1.0f && c0 <= 50.0f) ? 1.0f : 0.0f;
        float v1 = (c1 >= -1.0f && c1 <= 50.0f) ? 1.0f : 0.0f;
        float cl0 = fminf(fmaxf(c0, 0.0f), 49.0f);
        float cl1 = fminf(fmaxf(c1, 0.0f), 49.0f);
        int l0 = min(max((int)floorf(cl0), 0), 48);
        int l1 = min(max((int)floorf(cl1), 0), 48);
        float f0 = cl0 - (float)l0, g0 = 1.0f - f0;
        float f1 = cl1 - (float)l1, g1 = 1.0f - f1;
        int dq = l1 - l0;
        u0 = v0 * g0 + ((dq == 0) ? v1 * g1 : 0.0f);
        u1 = v0 * f0 + ((dq == 0) ? v1 * f1 : v1 * g1);
        u2 = (dq == 0) ? 0.0f : v1 * f1;
        xl0 = l0;
    }
    int ry0 = yl0 - rb;                      // 0..13
    int cc0 = xl0 - cb;                      // 0..13

    // ---- A rows in registers: cols hi*8+j of the 16-col window ----
    bf16x8 aw0, aw1, aw2;
    #pragma unroll
    for (int j = 0; j < 8; ++j) {
        int colj = hi * 8 + j;
        float uc = (colj == cc0) ? u0
                 : ((colj == cc0 + 1) ? u1 : ((colj == cc0 + 2) ? u2 : 0.0f));
        __hip_bfloat16 h0 = __float2bfloat16(wr0 * uc);
        __hip_bfloat16 h1 = __float2bfloat16(wr1 * uc);
        __hip_bfloat16 h2 = __float2bfloat16(wr2 * uc);
        aw0[j] = *(short*)&h0;
        aw1[j] = *(short*)&h1;
        aw2[j] = *(short*)&h2;
    }
    bf16x8 awz = {};

    // ---- staging helper: repack A regs -> given buffer ----
    auto stage = [&](short* buf) {
        u4v lo0, hi0, lo1, hi1;
        lo0[0] = (A0[0] & 0xffffu) | (A1[0] << 16);
        lo0[1] = (A2[0] & 0xffffu) | (A3[0] << 16);
        lo0[2] = (A4[0] & 0xffffu) | (A5[0] << 16);
        lo0[3] = (A6[0] & 0xffffu) | (A7[0] << 16);
        hi0[0] = (A0[0] >> 16) | (A1[0] & 0xffff0000u);
        hi0[1] = (A2[0] >> 16) | (A3[0] & 0xffff0000u);
        hi0[2] = (A4[0] >> 16) | (A5[0] & 0xffff0000u);
        hi0[3] = (A6[0] >> 16) | (A7[0] & 0xffff0000u);
        lo1[0] = (A0[1] & 0xffffu) | (A1[1] << 16);
        lo1[1] = (A2[1] & 0xffffu) | (A3[1] << 16);
        lo1[2] = (A4[1] & 0xffffu) | (A5[1] << 16);
        lo1[3] = (A6[1] & 0xffffu) | (A7[1] << 16);
        hi1[0] = (A0[1] >> 16) | (A1[1] & 0xffff0000u);
        hi1[1] = (A2[1] >> 16) | (A3[1] & 0xffff0000u);
        hi1[2] = (A4[1] >> 16) | (A5[1] & 0xffff0000u);
        hi1[3] = (A6[1] >> 16) | (A7[1] & 0xffff0000u);
        *(u4v*)&buf[(chA    ) * 64 + rotw * 8] = lo0;
        *(u4v*)&buf[(chA + 1) * 64 + rotw * 8] = hi0;
        *(u4v*)&buf[(chA + 2) * 64 + rotw * 8] = lo1;
        *(u4v*)&buf[(chA + 3) * 64 + rotw * 8] = hi1;
    };

    // ---- MFMA main loop: ping-pong, one barrier per chunk ----
    int ch0 = (wid & 1) * 32 + lane31;       // N-tile pair {ch0, ch0+64}
    int ch1 = ch0 + 64;
    int rot0 = ch0 >> 2, rot1 = ch1 >> 2;

    stage(Vl);                               // chunk 0 -> buf0
    __syncthreads();                         // buf0 ready

    f32x16 acc0 = {}, acc1 = {};
    for (int chunk = 0; chunk < nch; ++chunk) {
        short* cur = Vl + (chunk & 1) * (CG * 64);

        if (chunk + 1 < nch) {               // T14: issue next chunk's loads
            int r0 = rb + (chunk + 1) * 4 + tg;
            const unsigned int* rp = slabU + (r0 * WW + cb + half * 8) * 64 + 2 * cq;
            A0 = *(const u2v*)(rp);       A1 = *(const u2v*)(rp + 64);
            A2 = *(const u2v*)(rp + 128); A3 = *(const u2v*)(rp + 192);
            A4 = *(const u2v*)(rp + 256); A5 = *(const u2v*)(rp + 320);
            A6 = *(const u2v*)(rp + 384); A7 = *(const u2v*)(rp + 448);
        }

        #pragma unroll
        for (int kl = 0; kl < 4; ++kl) {
            int kk = chunk * 4 + kl;
            int rel = kk - ry0;
            bf16x8 av = (rel == 0) ? aw0
                      : ((rel == 1) ? aw1 : ((rel == 2) ? aw2 : awz));
            bf16x8 bv0 = *(const bf16x8*)&cur[ch0 * 64 + (((kl * 2 + hi) + rot0) & 7) * 8];
            bf16x8 bv1 = *(const bf16x8*)&cur[ch1 * 64 + (((kl * 2 + hi) + rot1) & 7) * 8];
            acc0 = __builtin_amdgcn_mfma_f32_32x32x16_bf16(av, bv0, acc0, 0, 0, 0);
            acc1 = __builtin_amdgcn_mfma_f32_32x32x16_bf16(av, bv1, acc1, 0, 0, 0);
        }

        if (chunk + 1 < nch) {
            stage(Vl + ((chunk + 1) & 1) * (CG * 64));
            __syncthreads();                 // next buf ready; prior reads drained
        }
    }
    __syncthreads();                         // all reads done; Vl reusable

    // ---- merged epilogue: stage BOTH acc passes into [128][52], 1 barrier --
    int m = wid >> 1;
    int obase = (n * C_TOTAL + g * CG) * NPOS;

    #pragma unroll
    for (int q = 0; q < 4; ++q) {
        int bin0 = m * 32 + 8 * q + 4 * hi;  // C/D row = (reg&3)+8*(reg>>2)+4*hi
        if (bin0 <= 48) {
            f4a v0, v1;
            v0[0] = acc0[4*q]; v0[1] = acc0[4*q+1];
            v0[2] = acc0[4*q+2]; v0[3] = acc0[4*q+3];
            v1[0] = acc1[4*q]; v1[1] = acc1[4*q+1];
            v1[2] = acc1[4*q+2]; v1[3] = acc1[4*q+3];
            *(f4a*)&solh[ch0 * 52 + bin0] = v0;          // ch 0..63
            *(f4a*)&solh[(ch0 + 64) * 52 + bin0] = v1;   // ch 64..127
        }
    }
    __syncthreads();

    // ---- single coalesced nontemporal writeback: 128*49/4 = 1568 f4a ----
    #pragma unroll
    for (int k2 = 0; k2 < 7; ++k2) {
        int t = k2 * 256 + tid;
        if (t < 1568) {
            f4a o;
            #pragma unroll
            for (int i2 = 0; i2 < 4; ++i2) {
                int f = 4 * t + i2;
                int fch = f / 49;
                int fbin = f - fch * 49;
                o[i2] = solh[fch * 52 + fbin] * 0.25f;
            }
            __builtin_nontemporal_store(o, (f4a*)(out + obase + 4 * t));
        }
    }
}

// ---- Fallback (fp32 direct, ~R7) if workspace too small --------------------
__global__ __launch_bounds__(256) void roi_align_fallback(
    const float* __restrict__ data, const float* __restrict__ rois,
    float* __restrict__ out, int H, int W, int N)
{
    __shared__ __align__(16) float so[64 * NPOS];
    int i   = blockIdx.x;
    int xcd = i & (NXCD - 1);
    int j   = i >> 3;
    int scl = (j >= N) ? 1 : 0;
    int n   = j - scl * N;
    int superchunk = xcd * 2 + scl;
    int t = threadIdx.x;
    bool active = (t < 5 * NPOS);
    int tt = active ? t : 0;
    int s  = tt % NPOS;
    int g  = tt / NPOS;
    int cbase = g * 13;
    int cnt = (g < 4) ? 13 : 12;
    int pw = s % PW;
    int ph = s / PW;
    if (active) {
        const float* roi = rois + n * 5;
        int   b  = (int)roi[0];
        float x1 = roi[1] * SPATIAL_SCALE, y1 = roi[2] * SPATIAL_SCALE;
        float x2 = roi[3] * SPATIAL_SCALE, y2 = roi[4] * SPATIAL_SCALE;
        float roi_w = fmaxf(x2 - x1, 1.0f), roi_h = fmaxf(y2 - y1, 1.0f);
        float bin_w = roi_w * (1.0f / PW), bin_h = roi_h * (1.0f / PH);
        float xc0 = x1 + ((float)(pw * 2 + 0) + 0.5f) * bin_w * 0.5f;
        float xc1 = x1 + ((float)(pw * 2 + 1) + 0.5f) * bin_w * 0.5f;
        float vx0 = (xc0 >= -1.0f && xc0 <= (float)W) ? 1.0f : 0.0f;
        float vx1 = (xc1 >= -1.0f && xc1 <= (float)W) ? 1.0f : 0.0f;
        float xcl0 = fminf(fmaxf(xc0, 0.0f), (float)(W - 1));
        float xcl1 = fminf(fmaxf(xc1, 0.0f), (float)(W - 1));
        int xl0 = min(max((int)floorf(xcl0), 0), W - 2);
        int xl1 = min(max((int)floorf(xcl1), 0), W - 2);
        float lx0 = xcl0 - (float)xl0, hx0 = 1.0f - lx0;
        float lx1 = xcl1 - (float)xl1, hx1 = 1.0f - lx1;
        int xb = min(xl0 & ~1, W - 4);
        int p0 = xl0 - xb, p1 = xl1 - xb;
        float w4[4];
        #pragma unroll
        for (int k = 0; k < 4; ++k) {
            float a = (p0 == k) ? hx0 : ((p0 + 1 == k) ? lx0 : 0.0f);
            float c = (p1 == k) ? hx1 : ((p1 + 1 == k) ? lx1 : 0.0f);
            w4[k] = vx0 * a + vx1 * c;
        }
        float yc0 = y1 + ((float)(ph * 2 + 0) + 0.5f) * bin_h * 0.5f;
        float yc1 = y1 + ((float)(ph * 2 + 1) + 0.5f) * bin_h * 0.5f;
        float vy0 = (yc0 >= -1.0f && yc0 <= (float)H) ? 1.0f : 0.0f;
        float vy1 = (yc1 >= -1.0f && yc1 <= (float)H) ? 1.0f : 0.0f;
        float ycl0 = fminf(fmaxf(yc0, 0.0f), (float)(H - 1));
        float ycl1 = fminf(fmaxf(yc1, 0.0f), (float)(H - 1));
        int yl0 = min(max((int)floorf(ycl0), 0), H - 2);
        int yl1 = min(max((int)floorf(ycl1), 0), H - 2);
        float ly0 = ycl0 - (float)yl0, hy0 = 1.0f - ly0;
        float ly1 = ycl1 - (float)yl1, hy1 = 1.0f - ly1;
        float wy0 = 0.25f * vy0 * hy0, wy1 = 0.25f * vy0 * ly0;
        float wy2 = 0.25f * vy1 * hy1, wy3 = 0.25f * vy1 * ly1;
        int q = yl1 - yl0;
        float wr0 = wy0 + ((q == 0) ? wy2 : 0.0f);
        float wr1 = wy1 + ((q == 0) ? wy3 : wy2);
        float wr2 = (q == 0) ? 0.0f : wy3;
        int row0 = yl0;
        int row2 = min(yl0 + 2, H - 1);
        float wv[3][4];
        #pragma unroll
        for (int k = 0; k < 4; ++k) {
            wv[0][k] = wr0 * w4[k]; wv[1][k] = wr1 * w4[k]; wv[2][k] = wr2 * w4[k];
        }
        int c0 = superchunk * 64 + cbase;
        const int HW = H * W;
        unsigned slab = (unsigned)(b * C_TOTAL + c0) * (unsigned)HW;
        unsigned o0 = slab + (unsigned)(row0 * W + xb);
        unsigned o1 = o0 + (unsigned)W;
        unsigned o2 = slab + (unsigned)(row2 * W + xb);
        int ldsbase = cbase * NPOS + s;
        f4v a0 = *(const f4v*)(data + o0);
        f4v a1 = *(const f4v*)(data + o1);
        f4v a2 = *(const f4v*)(data + o2);
        int jj = 0;
        for (; jj < cnt - 1; ++jj) {
            o0 += HW; o1 += HW; o2 += HW;
            f4v b0 = *(const f4v*)(data + o0);
            f4v b1 = *(const f4v*)(data + o1);
            f4v b2 = *(const f4v*)(data + o2);
            float acc = wv[0][0]*a0.x + wv[0][1]*a0.y + wv[0][2]*a0.z + wv[0][3]*a0.w
                      + wv[1][0]*a1.x + wv[1][1]*a1.y + wv[1][2]*a1.z + wv[1][3]*a1.w
                      + wv[2][0]*a2.x + wv[2][1]*a2.y + wv[2][2]*a2.z + wv[2][3]*a2.w;
            so[ldsbase + jj * NPOS] = acc;
            a0 = b0; a1 = b1; a2 = b2;
        }
        float acc = wv[0][0]*a0.x + wv[0][1]*a0.y + wv[0][2]*a0.z + wv[0][3]*a0.w
                  + wv[1][0]*a1.x + wv[1][1]*a1.y + wv[1][2]*a1.z + wv[1][3]*a1.w
                  + wv[2][0]*a2.x + wv[2][1]*a2.y + wv[2][2]*a2.z + wv[2][3]*a2.w;
        so[ldsbase + jj * NPOS] = acc;
    }
    __syncthreads();
    unsigned base = (unsigned)(n * C_TOTAL + superchunk * 64) * NPOS;
    f4a* dst = (f4a*)(out + base);
    const f4a* src = (const f4a*)so;
    int tid = threadIdx.x;
    dst[tid] = src[tid];
    dst[256 + tid] = src[256 + tid];
    dst[512 + tid] = src[512 + tid];
    if (tid < 16) dst[768 + tid] = src[768 + tid];
}

extern "C" void kernel_launch(void* const* d_in, const int* in_sizes, int n_in,
                              void* d_out, int out_size, void* d_ws, size_t ws_size,
                              hipStream_t stream) {
    const float* data = (const float*)d_in[0];
    const float* rois = (const float*)d_in[1];
    float* out = (float*)d_out;
    const int N = in_sizes[1] / 5;

    if (ws_size >= TB_BYTES) {
        __hip_bfloat16* Tb = (__hip_bfloat16*)d_ws;
        transpose_bf16_kernel<<<2 * HH * NXCD, 256, 0, stream>>>(data, Tb);
        roi_mfma_kernel<<<N * NXCD, 256, 0, stream>>>(
            (const unsigned int*)d_ws, rois, out, N);
    } else {
        roi_align_fallback<<<N * 16, 256, 0, stream>>>(data, rois, out, HH, WW, N);
    }
}